// Round 5
// baseline (804.033 us; speedup 1.0000x reference)
//
#include <hip/hip_runtime.h>
#include <math.h>

#define NUM_K 1024
#define DIM 256
#define HW 4096          // 64*64
#define NPIX 65536       // 16*4096
#define QELEMS 16777216  // 16*256*4096
#define MAX_FLAGS 16384

typedef short bf16x8 __attribute__((ext_vector_type(8)));
typedef float f32x4 __attribute__((ext_vector_type(4)));

__device__ __forceinline__ unsigned short f32_to_bf16_rne(float f) {
    unsigned int u = __float_as_uint(f);
    unsigned int r = u + 0x7FFFu + ((u >> 16) & 1u);
    return (unsigned short)(r >> 16);
}
__device__ __forceinline__ float bf16_to_f32(unsigned short h) {
    return __uint_as_float(((unsigned int)h) << 16);
}

// ---------------------------------------------------------------------------
// numpy-replicated f32 sum of squares over 256 elements (pairwise SIMD tree).
// (validated bit-exact vs harness numpy in rounds 2-4)
// ---------------------------------------------------------------------------
__device__ __forceinline__ float np_sumsq_256(const float* __restrict__ p, long stride) {
    float blk0 = 0.f, blk1 = 0.f;
#pragma unroll
    for (int h = 0; h < 2; ++h) {
        const float* base = p + (long)h * 128 * stride;
        float s[16];
#pragma unroll
        for (int L = 0; L < 16; ++L) {
            float a0 = base[(long)(L)       * stride]; a0 = __fmul_rn(a0, a0);
            float a1 = base[(long)(16 + L)  * stride]; a1 = __fmul_rn(a1, a1);
            float a2 = base[(long)(32 + L)  * stride]; a2 = __fmul_rn(a2, a2);
            float a3 = base[(long)(48 + L)  * stride]; a3 = __fmul_rn(a3, a3);
            float a4 = base[(long)(64 + L)  * stride]; a4 = __fmul_rn(a4, a4);
            float a5 = base[(long)(80 + L)  * stride]; a5 = __fmul_rn(a5, a5);
            float a6 = base[(long)(96 + L)  * stride]; a6 = __fmul_rn(a6, a6);
            float a7 = base[(long)(112 + L) * stride]; a7 = __fmul_rn(a7, a7);
            float t1 = __fadd_rn(a0, a1);
            float t2 = __fadd_rn(a2, a3);
            float t3 = __fadd_rn(a4, a5);
            float t4 = __fadd_rn(a6, a7);
            s[L] = __fadd_rn(__fadd_rn(t1, t2), __fadd_rn(t3, t4));
        }
        float c0 = __fadd_rn(s[0], s[8]);
        float c1 = __fadd_rn(s[1], s[9]);
        float c2 = __fadd_rn(s[2], s[10]);
        float c3 = __fadd_rn(s[3], s[11]);
        float c4 = __fadd_rn(s[4], s[12]);
        float c5 = __fadd_rn(s[5], s[13]);
        float c6 = __fadd_rn(s[6], s[14]);
        float c7 = __fadd_rn(s[7], s[15]);
        float d0 = __fadd_rn(c0, c4);
        float d1 = __fadd_rn(c1, c5);
        float d2 = __fadd_rn(c2, c6);
        float d3 = __fadd_rn(c3, c7);
        float e0 = __fadd_rn(d0, d2);
        float e1 = __fadd_rn(d1, d3);
        float r  = __fadd_rn(e0, e1);
        if (h == 0) blk0 = r; else blk1 = r;
    }
    return __fadd_rn(blk0, blk1);
}

__global__ __launch_bounds__(256) void k_wsq(const float* __restrict__ w, float* __restrict__ wsq) {
    int k = blockIdx.x * 256 + threadIdx.x;
    if (k < NUM_K) wsq[k] = np_sumsq_256(w + (long)k * DIM, 1);
}

__global__ __launch_bounds__(256) void k_xsq(const float* __restrict__ x, float* __restrict__ xsq) {
    int n = blockIdx.x * 256 + threadIdx.x;
    int b = n >> 12, hw = n & 4095;
    xsq[n] = np_sumsq_256(x + (long)b * DIM * HW + hw, HW);
}

// ---------- w transpose: wtr[d][k] = w[k][d], for coalesced refine loads ----------
__global__ __launch_bounds__(1024)
void k_wtrans(const float* __restrict__ w, float* __restrict__ wtr) {
    int d = blockIdx.x;
    int k = threadIdx.x;
    wtr[(long)d * NUM_K + k] = w[(long)k * DIM + d];
}

// ---------------------------------------------------------------------------
// w -> frag-major split-bf16 for B-frag of mfma_f32_16x16x32_bf16.
// ---------------------------------------------------------------------------
__global__ __launch_bounds__(256)
void k_wfrag(const float* __restrict__ w, short* __restrict__ whi, short* __restrict__ wlo) {
    int id = blockIdx.x * 256 + threadIdx.x;   // 32768 = 1024 codes * 32 chunks
    int code = id >> 5;
    int c = id & 31;                            // d-chunk of 8: d = c*8+j
    const float* src = w + (long)code * DIM + c * 8;
    unsigned short h[8], l[8];
#pragma unroll
    for (int j = 0; j < 8; ++j) {
        float v = src[j];
        unsigned short hh = f32_to_bf16_rne(v);
        float r = __fsub_rn(v, bf16_to_f32(hh));
        h[j] = hh;
        l[j] = f32_to_bf16_rne(r);
    }
    int fl = ((c & 3) << 4) | (code & 15);
    long addr = ((((long)(code >> 4) * 8 + (c >> 2)) * 64 + fl) * 8);
    bf16x8 vh, vl;
#pragma unroll
    for (int j = 0; j < 8; ++j) { vh[j] = (short)h[j]; vl[j] = (short)l[j]; }
    *(bf16x8*)(whi + addr) = vh;
    *(bf16x8*)(wlo + addr) = vl;
}

// ---------------------------------------------------------------------------
// MFMA argmin v5: block = 64 pixels x ALL 1024 codes, 8 waves (512 thr).
// Each wave: 64 px x 128 codes. A staged ONCE to LDS (shared by 8 waves);
// 2 blocks/CU -> 4 waves/SIMD. B prefetch-1. In-block cross-wave combine
// (ascending code order, lexicographic) writes idx + near-tie flags directly.
// ---------------------------------------------------------------------------
#define A_SLOT(ks,m,fl) ((((ks)*4+(m))*64+(fl))*8)

__global__ __launch_bounds__(512, 4)
void k_argmin_mfma(const float* __restrict__ x,
                   const short* __restrict__ whi, const short* __restrict__ wlo,
                   const float* __restrict__ wsq, const float* __restrict__ xsq,
                   int* __restrict__ idx, int* __restrict__ flags, int* __restrict__ flag_count) {
    __shared__ short ahi[8 * 4 * 64 * 8];   // 32KB [ks][m][fl][j]
    __shared__ short alo[8 * 4 * 64 * 8];   // 32KB
    __shared__ float cd1[8][64];
    __shared__ float cd2[8][64];
    __shared__ int   ci1[8][64];

    const int t = threadIdx.x;
    const int lane = t & 63;
    const int q = t >> 6;                    // wave id 0..7
    const int tile = blockIdx.x;             // 1024 pixel tiles of 64

    const int b = tile >> 6;
    const int hw0 = (tile & 63) * 64;
    const float* xb = x + (long)b * (DIM * HW) + hw0 + lane;

    // ---- stage A once: 512 threads x 4 chunks = 2048 chunk-stores ----
#pragma unroll
    for (int i = 0; i < 4; ++i) {
        int c = q * 4 + i;                   // d-chunk 0..31 (8 dims each)
        float v[8];
#pragma unroll
        for (int jj = 0; jj < 8; ++jj) v[jj] = xb[(long)(c * 8 + jj) * HW];
        bf16x8 vh, vl;
#pragma unroll
        for (int jj = 0; jj < 8; ++jj) {
            unsigned short hh = f32_to_bf16_rne(v[jj]);
            float r = __fsub_rn(v[jj], bf16_to_f32(hh));
            vh[jj] = (short)hh;
            vl[jj] = (short)f32_to_bf16_rne(r);
        }
        int slot = A_SLOT(c >> 2, lane >> 4, ((c & 3) << 4) | (lane & 15));
        *(bf16x8*)(ahi + slot) = vh;
        *(bf16x8*)(alo + slot) = vl;
    }
    __syncthreads();

    const int ct0 = q * 8;                   // this wave's 16-code-tile base
    f32x4 acc[4][8];
#pragma unroll
    for (int m = 0; m < 4; ++m)
#pragma unroll
        for (int n = 0; n < 8; ++n) acc[m][n] = (f32x4){0.f, 0.f, 0.f, 0.f};

    for (int ks = 0; ks < 8; ++ks) {
        bf16x8 ah[4], al[4];
#pragma unroll
        for (int m = 0; m < 4; ++m) {
            ah[m] = *(const bf16x8*)(ahi + A_SLOT(ks, m, lane));
            al[m] = *(const bf16x8*)(alo + A_SLOT(ks, m, lane));
        }
        // B addresses: stride between n-tiles = 8*64*8 shorts
        long baddr0 = (((long)ct0 * 8 + ks) * 64 + lane) * 8;
        bf16x8 bh = *(const bf16x8*)(whi + baddr0);
        bf16x8 bl = *(const bf16x8*)(wlo + baddr0);
#pragma unroll
        for (int n = 0; n < 8; ++n) {
            bf16x8 nbh = bh, nbl = bl;
            if (n < 7) {
                long ba = baddr0 + (long)(n + 1) * (8 * 64 * 8);
                nbh = *(const bf16x8*)(whi + ba);
                nbl = *(const bf16x8*)(wlo + ba);
            }
#pragma unroll
            for (int m = 0; m < 4; ++m) {
                acc[m][n] = __builtin_amdgcn_mfma_f32_16x16x32_bf16(ah[m], bh, acc[m][n], 0, 0, 0);
                acc[m][n] = __builtin_amdgcn_mfma_f32_16x16x32_bf16(al[m], bh, acc[m][n], 0, 0, 0);
                acc[m][n] = __builtin_amdgcn_mfma_f32_16x16x32_bf16(ah[m], bl, acc[m][n], 0, 0, 0);
            }
            bh = nbh; bl = nbl;
        }
    }

    // ---- epilogue: dist = fl(fl(s1+wsq) - 2*dot); per-lane (d1,d2,i1) ----
    const long px0 = (long)tile * 64;
    const int rbase = (lane >> 4) * 4;
    float s1v[4][4];
#pragma unroll
    for (int m = 0; m < 4; ++m)
#pragma unroll
        for (int r = 0; r < 4; ++r) s1v[m][r] = xsq[px0 + 16 * m + rbase + r];

    float bd1[4][4], bd2[4][4];
    int bi1[4][4];
#pragma unroll
    for (int m = 0; m < 4; ++m)
#pragma unroll
        for (int r = 0; r < 4; ++r) { bd1[m][r] = INFINITY; bd2[m][r] = INFINITY; bi1[m][r] = 0; }

#pragma unroll
    for (int n = 0; n < 8; ++n) {
        int code = (ct0 + n) * 16 + (lane & 15);
        float wq = wsq[code];
#pragma unroll
        for (int m = 0; m < 4; ++m) {
#pragma unroll
            for (int r = 0; r < 4; ++r) {
                float tt = __fadd_rn(s1v[m][r], wq);
                float dist = __fmaf_rn(-2.0f, acc[m][n][r], tt);
                bool c1 = dist < bd1[m][r];
                bool c2 = dist < bd2[m][r];
                bd2[m][r] = c1 ? bd1[m][r] : (c2 ? dist : bd2[m][r]);
                bd1[m][r] = c1 ? dist : bd1[m][r];
                bi1[m][r] = c1 ? code : bi1[m][r];
            }
        }
    }

    // butterfly across the 16 lanes holding different codes
#pragma unroll
    for (int step = 1; step < 16; step <<= 1) {
#pragma unroll
        for (int m = 0; m < 4; ++m) {
#pragma unroll
            for (int r = 0; r < 4; ++r) {
                float od1 = __shfl_xor(bd1[m][r], step);
                float od2 = __shfl_xor(bd2[m][r], step);
                int   oi  = __shfl_xor(bi1[m][r], step);
                bool take = (od1 < bd1[m][r]) || ((od1 == bd1[m][r]) && (oi < bi1[m][r]));
                float nd2 = fminf(fmaxf(od1, bd1[m][r]), fminf(od2, bd2[m][r]));
                bd1[m][r] = take ? od1 : bd1[m][r];
                bi1[m][r] = take ? oi : bi1[m][r];
                bd2[m][r] = nd2;
            }
        }
    }

    // per-wave results -> LDS
    if ((lane & 15) == 0) {
#pragma unroll
        for (int m = 0; m < 4; ++m) {
#pragma unroll
            for (int r = 0; r < 4; ++r) {
                int px = 16 * m + rbase + r;
                cd1[q][px] = bd1[m][r];
                cd2[q][px] = bd2[m][r];
                ci1[q][px] = bi1[m][r];
            }
        }
    }
    __syncthreads();

    // cross-wave combine (ascending code order) + idx/flag write
    if (t < 64) {
        float d1 = cd1[0][t], d2 = cd2[0][t];
        int i1 = ci1[0][t];
#pragma unroll
        for (int s = 1; s < 8; ++s) {
            float a1 = cd1[s][t];
            float a2 = cd2[s][t];
            int   ai = ci1[s][t];
            bool take = (a1 < d1) || ((a1 == d1) && (ai < i1));
            float nd2 = fminf(fmaxf(a1, d1), fminf(a2, d2));
            d1 = take ? a1 : d1;
            i1 = take ? ai : i1;
            d2 = nd2;
        }
        const long n = px0 + t;
        idx[n] = i1;
        if (__fsub_rn(d2, d1) <= d1 * 6.0e-7f) {
            int pos = atomicAdd(flag_count, 1);
            if (pos < MAX_FLAGS) flags[pos] = (int)n;
        }
    }
}

// ---------- fallback VALU argmin (round-2 proven path) ----------
__global__ __launch_bounds__(256, 2)
void k_argmin_valu(const float* __restrict__ x, const float* __restrict__ w,
                   const float* __restrict__ wsq, const float* __restrict__ xsq,
                   int* __restrict__ idx, int* __restrict__ flags, int* __restrict__ flag_count) {
    __shared__ float xs[64 * 257];
    __shared__ float sd1[4][64];
    __shared__ float sd2[4][64];
    __shared__ int   si1[4][64];

    const int t = threadIdx.x;
    const int p = t & 63;
    const int q = t >> 6;
    const long n0 = (long)blockIdx.x * 64;
    const int b = (int)(n0 >> 12);
    const int hw0 = (int)(n0 & 4095);
    const float* xb = x + (long)b * DIM * HW + hw0;

    for (int i = 0; i < 64; ++i) {
        int c = q * 64 + i;
        xs[p * 257 + c] = xb[(long)c * HW + p];
    }
    __syncthreads();

    const float* xrow = xs + p * 257;
    const float s1 = xsq[n0 + p];
    float d1 = INFINITY, d2 = INFINITY;
    int i1 = 0;
    const int kbase = q * 256;
    const float* wq = w + (long)kbase * DIM;
    const float* wsq_q = wsq + kbase;

    for (int kc = 0; kc < 256; kc += 8) {
        float acc[8] = {0.f, 0.f, 0.f, 0.f, 0.f, 0.f, 0.f, 0.f};
        const float* w0 = wq + (long)kc * DIM;
#pragma unroll 2
        for (int d = 0; d < DIM; d += 4) {
            float x0 = xrow[d + 0];
            float x1 = xrow[d + 1];
            float x2 = xrow[d + 2];
            float x3 = xrow[d + 3];
#pragma unroll
            for (int j = 0; j < 8; ++j) {
                const float4 wv = *reinterpret_cast<const float4*>(w0 + j * DIM + d);
                acc[j] = __fmaf_rn(x0, wv.x, acc[j]);
                acc[j] = __fmaf_rn(x1, wv.y, acc[j]);
                acc[j] = __fmaf_rn(x2, wv.z, acc[j]);
                acc[j] = __fmaf_rn(x3, wv.w, acc[j]);
            }
        }
#pragma unroll
        for (int j = 0; j < 8; ++j) {
            float tk = __fadd_rn(s1, wsq_q[kc + j]);
            float dist = __fsub_rn(tk, __fmul_rn(2.0f, acc[j]));
            if (dist < d1) { d2 = d1; d1 = dist; i1 = kbase + kc + j; }
            else if (dist < d2) { d2 = dist; }
        }
    }

    sd1[q][p] = d1; sd2[q][p] = d2; si1[q][p] = i1;
    __syncthreads();
    if (q == 0) {
        float bd1 = sd1[0][p], bd2 = sd2[0][p];
        int bi = si1[0][p];
#pragma unroll
        for (int j = 1; j < 4; ++j) {
            float a1 = sd1[j][p], a2 = sd2[j][p];
            int ai = si1[j][p];
            if (a1 < bd1) { bd2 = fminf(bd1, a2); bd1 = a1; bi = ai; }
            else { bd2 = fminf(bd2, fminf(a1, a2)); }
        }
        const long n = n0 + p;
        idx[n] = bi;
        if (__fsub_rn(bd2, bd1) <= bd1 * 6.0e-7f) {
            int pos = atomicAdd(flag_count, 1);
            if (pos < MAX_FLAGS) flags[pos] = (int)n;
        }
    }
}

// ---------------------------------------------------------------------------
// exact-dot refine: one block per flagged pixel, 1024 threads = 1 code each.
// (round-4 proven: coalesced wT loads, f64 exact, first-index tie-break)
// ---------------------------------------------------------------------------
__global__ __launch_bounds__(1024)
void k_refine(const float* __restrict__ x, const float* __restrict__ wtr,
              const float* __restrict__ wsq, const float* __restrict__ xsq,
              const int* __restrict__ flags, const int* __restrict__ flag_count,
              int* __restrict__ idx) {
    __shared__ float xsf[DIM];
    __shared__ float rd[1024];
    __shared__ int   ri[1024];
    int nf = *flag_count;
    if (nf > MAX_FLAGS) nf = MAX_FLAGS;
    const int t = threadIdx.x;
    for (int fi = blockIdx.x; fi < nf; fi += gridDim.x) {
        int n = flags[fi];
        int b = n >> 12, hw = n & 4095;
        const float* xp = x + (long)b * DIM * HW + hw;
        __syncthreads();
        if (t < DIM) xsf[t] = xp[(long)t * HW];
        __syncthreads();
        const float s1 = xsq[n];
        double a0 = 0.0, a1 = 0.0, a2 = 0.0, a3 = 0.0;
#pragma unroll 8
        for (int d = 0; d < DIM; d += 4) {
            a0 = fma((double)wtr[(long)(d + 0) * NUM_K + t], (double)xsf[d + 0], a0);
            a1 = fma((double)wtr[(long)(d + 1) * NUM_K + t], (double)xsf[d + 1], a1);
            a2 = fma((double)wtr[(long)(d + 2) * NUM_K + t], (double)xsf[d + 2], a2);
            a3 = fma((double)wtr[(long)(d + 3) * NUM_K + t], (double)xsf[d + 3], a3);
        }
        float dots = (float)((a0 + a1) + (a2 + a3));
        float dk = __fsub_rn(__fadd_rn(s1, wsq[t]), __fmul_rn(2.0f, dots));
        rd[t] = dk; ri[t] = t;
        __syncthreads();
        for (int s = 512; s > 0; s >>= 1) {
            if (t < s) {
                float ra = rd[t + s]; int ia = ri[t + s];
                if (ra < rd[t] || (ra == rd[t] && ia < ri[t])) { rd[t] = ra; ri[t] = ia; }
            }
            __syncthreads();
        }
        if (t == 0) idx[n] = ri[0];
    }
}

// ---------- gather + straight-through + loss ----------
__global__ __launch_bounds__(256, 2)
void k_quant(const float* __restrict__ x, const float* __restrict__ w,
             const int* __restrict__ idx, float* __restrict__ qout,
             float* __restrict__ iout, float* __restrict__ loss) {
    __shared__ float wrow[64 * 257];
    __shared__ int lidx[64];
    __shared__ float part[4];
    const int t = threadIdx.x;
    const long n0 = (long)blockIdx.x * 64;
    const int b = (int)(n0 >> 12), hw0 = (int)(n0 & 4095);

    if (t < 64) lidx[t] = idx[n0 + t];
    __syncthreads();
    for (int i = 0; i < 64; ++i) {
        wrow[i * 257 + t] = w[(long)lidx[i] * DIM + t];
    }
    if (t < 64) iout[n0 + t] = (float)lidx[t];
    __syncthreads();

    const int p = t & 63, cg = t >> 6;
    const float* xb = x + (long)b * DIM * HW + hw0;
    float* qb = qout + (long)b * DIM * HW + hw0;
    float lsum = 0.f;
    for (int i = 0; i < 64; ++i) {
        int c = cg * 64 + i;
        float qv = wrow[p * 257 + c];
        long off = (long)c * HW + p;
        float xv = xb[off];
        float diff = __fsub_rn(qv, xv);
        qb[off] = __fadd_rn(xv, diff);
        lsum = __fmaf_rn(diff, diff, lsum);
    }
#pragma unroll
    for (int off = 32; off; off >>= 1) lsum += __shfl_down(lsum, off);
    if ((t & 63) == 0) part[t >> 6] = lsum;
    __syncthreads();
    if (t == 0) {
        float tot = (part[0] + part[1]) + (part[2] + part[3]);
        atomicAdd(loss, tot * (1.25f / 16777216.f));
    }
}

extern "C" void kernel_launch(void* const* d_in, const int* in_sizes, int n_in,
                              void* d_out, int out_size, void* d_ws, size_t ws_size,
                              hipStream_t stream) {
    const float* x = (const float*)d_in[0];
    const float* w = (const float*)d_in[1];

    float* qout = (float*)d_out;
    float* iout = qout + QELEMS;
    float* loss = iout + NPIX;

    char* wp = (char*)d_ws;
    int*   idx        = (int*)wp;                 wp += (size_t)NPIX * 4;        // 256KB
    float* wsq        = (float*)wp;               wp += (size_t)NUM_K * 4;       // 4KB
    float* xsq        = (float*)wp;               wp += (size_t)NPIX * 4;        // 256KB
    int*   flags      = (int*)wp;                 wp += (size_t)MAX_FLAGS * 4;   // 64KB
    int*   flag_count = (int*)wp;                 wp += 256;
    float* wtr        = (float*)wp;               wp += (size_t)NUM_K * DIM * 4; // 1MB
    short* whi        = (short*)wp;               wp += (size_t)NUM_K * DIM * 2; // 512KB
    short* wlo        = (short*)wp;               wp += (size_t)NUM_K * DIM * 2; // 512KB
    size_t need = (size_t)(wp - (char*)d_ws);

    hipMemsetAsync(loss, 0, sizeof(float), stream);
    hipMemsetAsync(flag_count, 0, sizeof(int), stream);

    k_wsq<<<4, 256, 0, stream>>>(w, wsq);
    k_xsq<<<NPIX / 256, 256, 0, stream>>>(x, xsq);
    k_wtrans<<<DIM, 1024, 0, stream>>>(w, wtr);

    if (ws_size >= need) {
        k_wfrag<<<128, 256, 0, stream>>>(w, whi, wlo);
        k_argmin_mfma<<<1024, 512, 0, stream>>>(x, whi, wlo, wsq, xsq, idx, flags, flag_count);
    } else {
        k_argmin_valu<<<NPIX / 64, 256, 0, stream>>>(x, w, wsq, xsq, idx, flags, flag_count);
    }
    k_refine<<<2048, 1024, 0, stream>>>(x, wtr, wsq, xsq, flags, flag_count, idx);
    k_quant<<<NPIX / 64, 256, 0, stream>>>(x, w, idx, qout, iout, loss);
}

// Round 6
// 352.270 us; speedup vs baseline: 2.2824x; 2.2824x over previous
//
#include <hip/hip_runtime.h>
#include <math.h>

#define NUM_K 1024
#define DIM 256
#define HW 4096          // 64*64
#define NPIX 65536       // 16*4096
#define QELEMS 16777216  // 16*256*4096
#define MAX_FLAGS 16384

typedef short bf16x8 __attribute__((ext_vector_type(8)));
typedef float f32x4 __attribute__((ext_vector_type(4)));

__device__ __forceinline__ unsigned short f32_to_bf16_rne(float f) {
    unsigned int u = __float_as_uint(f);
    unsigned int r = u + 0x7FFFu + ((u >> 16) & 1u);
    return (unsigned short)(r >> 16);
}
__device__ __forceinline__ float bf16_to_f32(unsigned short h) {
    return __uint_as_float(((unsigned int)h) << 16);
}

// ---------------------------------------------------------------------------
// numpy-replicated f32 sum of squares over 256 elements (pairwise SIMD tree).
// (validated bit-exact vs harness numpy in rounds 2-5)
// ---------------------------------------------------------------------------
__device__ __forceinline__ float np_sumsq_256(const float* __restrict__ p, long stride) {
    float blk0 = 0.f, blk1 = 0.f;
#pragma unroll
    for (int h = 0; h < 2; ++h) {
        const float* base = p + (long)h * 128 * stride;
        float s[16];
#pragma unroll
        for (int L = 0; L < 16; ++L) {
            float a0 = base[(long)(L)       * stride]; a0 = __fmul_rn(a0, a0);
            float a1 = base[(long)(16 + L)  * stride]; a1 = __fmul_rn(a1, a1);
            float a2 = base[(long)(32 + L)  * stride]; a2 = __fmul_rn(a2, a2);
            float a3 = base[(long)(48 + L)  * stride]; a3 = __fmul_rn(a3, a3);
            float a4 = base[(long)(64 + L)  * stride]; a4 = __fmul_rn(a4, a4);
            float a5 = base[(long)(80 + L)  * stride]; a5 = __fmul_rn(a5, a5);
            float a6 = base[(long)(96 + L)  * stride]; a6 = __fmul_rn(a6, a6);
            float a7 = base[(long)(112 + L) * stride]; a7 = __fmul_rn(a7, a7);
            float t1 = __fadd_rn(a0, a1);
            float t2 = __fadd_rn(a2, a3);
            float t3 = __fadd_rn(a4, a5);
            float t4 = __fadd_rn(a6, a7);
            s[L] = __fadd_rn(__fadd_rn(t1, t2), __fadd_rn(t3, t4));
        }
        float c0 = __fadd_rn(s[0], s[8]);
        float c1 = __fadd_rn(s[1], s[9]);
        float c2 = __fadd_rn(s[2], s[10]);
        float c3 = __fadd_rn(s[3], s[11]);
        float c4 = __fadd_rn(s[4], s[12]);
        float c5 = __fadd_rn(s[5], s[13]);
        float c6 = __fadd_rn(s[6], s[14]);
        float c7 = __fadd_rn(s[7], s[15]);
        float d0 = __fadd_rn(c0, c4);
        float d1 = __fadd_rn(c1, c5);
        float d2 = __fadd_rn(c2, c6);
        float d3 = __fadd_rn(c3, c7);
        float e0 = __fadd_rn(d0, d2);
        float e1 = __fadd_rn(d1, d3);
        float r  = __fadd_rn(e0, e1);
        if (h == 0) blk0 = r; else blk1 = r;
    }
    return __fadd_rn(blk0, blk1);
}

__global__ __launch_bounds__(256) void k_wsq(const float* __restrict__ w, float* __restrict__ wsq) {
    int k = blockIdx.x * 256 + threadIdx.x;
    if (k < NUM_K) wsq[k] = np_sumsq_256(w + (long)k * DIM, 1);
}

__global__ __launch_bounds__(256) void k_xsq(const float* __restrict__ x, float* __restrict__ xsq) {
    int n = blockIdx.x * 256 + threadIdx.x;
    int b = n >> 12, hw = n & 4095;
    xsq[n] = np_sumsq_256(x + (long)b * DIM * HW + hw, HW);
}

// ---------- w transpose: wtr[d][k] = w[k][d], for coalesced refine loads ----------
__global__ __launch_bounds__(1024)
void k_wtrans(const float* __restrict__ w, float* __restrict__ wtr) {
    int d = blockIdx.x;
    int k = threadIdx.x;
    wtr[(long)d * NUM_K + k] = w[(long)k * DIM + d];
}

// ---------------------------------------------------------------------------
// w -> frag-major split-bf16 for B-frag of mfma_f32_16x16x32_bf16.
// ---------------------------------------------------------------------------
__global__ __launch_bounds__(256)
void k_wfrag(const float* __restrict__ w, short* __restrict__ whi, short* __restrict__ wlo) {
    int id = blockIdx.x * 256 + threadIdx.x;   // 32768 = 1024 codes * 32 chunks
    int code = id >> 5;
    int c = id & 31;                            // d-chunk of 8: d = c*8+j
    const float* src = w + (long)code * DIM + c * 8;
    unsigned short h[8], l[8];
#pragma unroll
    for (int j = 0; j < 8; ++j) {
        float v = src[j];
        unsigned short hh = f32_to_bf16_rne(v);
        float r = __fsub_rn(v, bf16_to_f32(hh));
        h[j] = hh;
        l[j] = f32_to_bf16_rne(r);
    }
    int fl = ((c & 3) << 4) | (code & 15);
    long addr = ((((long)(code >> 4) * 8 + (c >> 2)) * 64 + fl) * 8);
    bf16x8 vh, vl;
#pragma unroll
    for (int j = 0; j < 8; ++j) { vh[j] = (short)h[j]; vl[j] = (short)l[j]; }
    *(bf16x8*)(whi + addr) = vh;
    *(bf16x8*)(wlo + addr) = vl;
}

// ---------------------------------------------------------------------------
// MFMA argmin v6: block = 32 pixels x 512 codes, 4 waves (256 thr).
// Each wave: 32 px x 128 codes -> acc[2][8] = 64 regs (half of v4) so the
// kernel fits ~3-4 waves/SIMD WITHOUT forced caps (round-5 spill lesson).
// A staged to 32KB LDS; B streamed from L2 with prefetch-1; per-wave
// (d1,d2,i1) partials written for k_combine (round-3 proven path).
// ---------------------------------------------------------------------------
#define A_SLOT(ks,m,fl) ((((ks)*2+(m))*64+(fl))*8)

__global__ __launch_bounds__(256, 3)
void k_argmin_mfma(const float* __restrict__ x,
                   const short* __restrict__ whi, const short* __restrict__ wlo,
                   const float* __restrict__ wsq, const float* __restrict__ xsq,
                   float* __restrict__ pd1, float* __restrict__ pd2, int* __restrict__ pi1) {
    __shared__ short ahi[8 * 2 * 64 * 8];   // 16KB [ks][m][fl][j]
    __shared__ short alo[8 * 2 * 64 * 8];   // 16KB

    const int t = threadIdx.x;
    const int lane = t & 63;
    const int q = t >> 6;                    // wave id 0..3
    const int tile = blockIdx.x >> 1;        // 2048 pixel tiles of 32
    const int slice = blockIdx.x & 1;        // code slice of 512

    const int b = tile >> 7;                 // 128 tiles per image
    const int hw0 = (tile & 127) * 32;

    // ---- stage A: 32px x 256d, thread t handles px=t&31, 4 chunks of 8 d ----
    {
        const int p = t & 31;
        const int g = t >> 5;                // 0..7
        const float* xb = x + (long)b * (DIM * HW) + hw0 + p;
#pragma unroll
        for (int i = 0; i < 4; ++i) {
            int c = g * 4 + i;               // d-chunk 0..31
            float v[8];
#pragma unroll
            for (int jj = 0; jj < 8; ++jj) v[jj] = xb[(long)(c * 8 + jj) * HW];
            bf16x8 vh, vl;
#pragma unroll
            for (int jj = 0; jj < 8; ++jj) {
                unsigned short hh = f32_to_bf16_rne(v[jj]);
                float r = __fsub_rn(v[jj], bf16_to_f32(hh));
                vh[jj] = (short)hh;
                vl[jj] = (short)f32_to_bf16_rne(r);
            }
            int slot = A_SLOT(c >> 2, p >> 4, ((c & 3) << 4) | (p & 15));
            *(bf16x8*)(ahi + slot) = vh;
            *(bf16x8*)(alo + slot) = vl;
        }
    }
    __syncthreads();

    const int ct0 = slice * 32 + q * 8;      // this wave's 16-code-tile base
    f32x4 acc[2][8];
#pragma unroll
    for (int m = 0; m < 2; ++m)
#pragma unroll
        for (int n = 0; n < 8; ++n) acc[m][n] = (f32x4){0.f, 0.f, 0.f, 0.f};

    for (int ks = 0; ks < 8; ++ks) {
        bf16x8 ah[2], al[2];
#pragma unroll
        for (int m = 0; m < 2; ++m) {
            ah[m] = *(const bf16x8*)(ahi + A_SLOT(ks, m, lane));
            al[m] = *(const bf16x8*)(alo + A_SLOT(ks, m, lane));
        }
        long baddr0 = (((long)ct0 * 8 + ks) * 64 + lane) * 8;
        bf16x8 bh = *(const bf16x8*)(whi + baddr0);
        bf16x8 bl = *(const bf16x8*)(wlo + baddr0);
#pragma unroll
        for (int n = 0; n < 8; ++n) {
            bf16x8 nbh = bh, nbl = bl;
            if (n < 7) {
                long ba = baddr0 + (long)(n + 1) * (8 * 64 * 8);
                nbh = *(const bf16x8*)(whi + ba);
                nbl = *(const bf16x8*)(wlo + ba);
            }
#pragma unroll
            for (int m = 0; m < 2; ++m) {
                acc[m][n] = __builtin_amdgcn_mfma_f32_16x16x32_bf16(ah[m], bh, acc[m][n], 0, 0, 0);
                acc[m][n] = __builtin_amdgcn_mfma_f32_16x16x32_bf16(al[m], bh, acc[m][n], 0, 0, 0);
                acc[m][n] = __builtin_amdgcn_mfma_f32_16x16x32_bf16(ah[m], bl, acc[m][n], 0, 0, 0);
            }
            bh = nbh; bl = nbl;
        }
    }

    // ---- epilogue: dist = fl(fl(s1+wsq) - 2*dot); per-lane (d1,d2,i1) ----
    const long px0 = (long)tile * 32;
    const int rbase = (lane >> 4) * 4;
    float s1v[2][4];
#pragma unroll
    for (int m = 0; m < 2; ++m)
#pragma unroll
        for (int r = 0; r < 4; ++r) s1v[m][r] = xsq[px0 + 16 * m + rbase + r];

    float bd1[2][4], bd2[2][4];
    int bi1[2][4];
#pragma unroll
    for (int m = 0; m < 2; ++m)
#pragma unroll
        for (int r = 0; r < 4; ++r) { bd1[m][r] = INFINITY; bd2[m][r] = INFINITY; bi1[m][r] = 0; }

#pragma unroll
    for (int n = 0; n < 8; ++n) {
        int code = (ct0 + n) * 16 + (lane & 15);
        float wq = wsq[code];
#pragma unroll
        for (int m = 0; m < 2; ++m) {
#pragma unroll
            for (int r = 0; r < 4; ++r) {
                float tt = __fadd_rn(s1v[m][r], wq);
                float dist = __fmaf_rn(-2.0f, acc[m][n][r], tt);
                bool c1 = dist < bd1[m][r];
                bool c2 = dist < bd2[m][r];
                bd2[m][r] = c1 ? bd1[m][r] : (c2 ? dist : bd2[m][r]);
                bd1[m][r] = c1 ? dist : bd1[m][r];
                bi1[m][r] = c1 ? code : bi1[m][r];
            }
        }
    }

    // butterfly across the 16 lanes holding different codes
#pragma unroll
    for (int step = 1; step < 16; step <<= 1) {
#pragma unroll
        for (int m = 0; m < 2; ++m) {
#pragma unroll
            for (int r = 0; r < 4; ++r) {
                float od1 = __shfl_xor(bd1[m][r], step);
                float od2 = __shfl_xor(bd2[m][r], step);
                int   oi  = __shfl_xor(bi1[m][r], step);
                bool take = (od1 < bd1[m][r]) || ((od1 == bd1[m][r]) && (oi < bi1[m][r]));
                float nd2 = fminf(fmaxf(od1, bd1[m][r]), fminf(od2, bd2[m][r]));
                bd1[m][r] = take ? od1 : bd1[m][r];
                bi1[m][r] = take ? oi : bi1[m][r];
                bd2[m][r] = nd2;
            }
        }
    }

    if ((lane & 15) == 0) {
        const long ws_id = slice * 4 + q;    // ascending code order
#pragma unroll
        for (int m = 0; m < 2; ++m) {
#pragma unroll
            for (int r = 0; r < 4; ++r) {
                long pix = px0 + 16 * m + rbase + r;
                pd1[ws_id * NPIX + pix] = bd1[m][r];
                pd2[ws_id * NPIX + pix] = bd2[m][r];
                pi1[ws_id * NPIX + pix] = bi1[m][r];
            }
        }
    }
}

// ---------- combine 8 code-slice partials, flag near-ties (round-3 proven) ----------
__global__ __launch_bounds__(256)
void k_combine(const float* __restrict__ pd1, const float* __restrict__ pd2,
               const int* __restrict__ pi1, int* __restrict__ idx,
               int* __restrict__ flags, int* __restrict__ flag_count) {
    int n = blockIdx.x * 256 + threadIdx.x;
    float d1 = pd1[n], d2 = pd2[n];
    int i1 = pi1[n];
#pragma unroll
    for (int s = 1; s < 8; ++s) {
        float a1 = pd1[(long)s * NPIX + n];
        float a2 = pd2[(long)s * NPIX + n];
        int   ai = pi1[(long)s * NPIX + n];
        bool take = (a1 < d1) || ((a1 == d1) && (ai < i1));
        float nd2 = fminf(fmaxf(a1, d1), fminf(a2, d2));
        d1 = take ? a1 : d1;
        i1 = take ? ai : i1;
        d2 = nd2;
    }
    idx[n] = i1;
    if (__fsub_rn(d2, d1) <= d1 * 6.0e-7f) {
        int pos = atomicAdd(flag_count, 1);
        if (pos < MAX_FLAGS) flags[pos] = n;
    }
}

// ---------- fallback VALU argmin (round-2 proven path) ----------
__global__ __launch_bounds__(256, 2)
void k_argmin_valu(const float* __restrict__ x, const float* __restrict__ w,
                   const float* __restrict__ wsq, const float* __restrict__ xsq,
                   int* __restrict__ idx, int* __restrict__ flags, int* __restrict__ flag_count) {
    __shared__ float xs[64 * 257];
    __shared__ float sd1[4][64];
    __shared__ float sd2[4][64];
    __shared__ int   si1[4][64];

    const int t = threadIdx.x;
    const int p = t & 63;
    const int q = t >> 6;
    const long n0 = (long)blockIdx.x * 64;
    const int b = (int)(n0 >> 12);
    const int hw0 = (int)(n0 & 4095);
    const float* xb = x + (long)b * DIM * HW + hw0;

    for (int i = 0; i < 64; ++i) {
        int c = q * 64 + i;
        xs[p * 257 + c] = xb[(long)c * HW + p];
    }
    __syncthreads();

    const float* xrow = xs + p * 257;
    const float s1 = xsq[n0 + p];
    float d1 = INFINITY, d2 = INFINITY;
    int i1 = 0;
    const int kbase = q * 256;
    const float* wq = w + (long)kbase * DIM;
    const float* wsq_q = wsq + kbase;

    for (int kc = 0; kc < 256; kc += 8) {
        float acc[8] = {0.f, 0.f, 0.f, 0.f, 0.f, 0.f, 0.f, 0.f};
        const float* w0 = wq + (long)kc * DIM;
#pragma unroll 2
        for (int d = 0; d < DIM; d += 4) {
            float x0 = xrow[d + 0];
            float x1 = xrow[d + 1];
            float x2 = xrow[d + 2];
            float x3 = xrow[d + 3];
#pragma unroll
            for (int j = 0; j < 8; ++j) {
                const float4 wv = *reinterpret_cast<const float4*>(w0 + j * DIM + d);
                acc[j] = __fmaf_rn(x0, wv.x, acc[j]);
                acc[j] = __fmaf_rn(x1, wv.y, acc[j]);
                acc[j] = __fmaf_rn(x2, wv.z, acc[j]);
                acc[j] = __fmaf_rn(x3, wv.w, acc[j]);
            }
        }
#pragma unroll
        for (int j = 0; j < 8; ++j) {
            float tk = __fadd_rn(s1, wsq_q[kc + j]);
            float dist = __fsub_rn(tk, __fmul_rn(2.0f, acc[j]));
            if (dist < d1) { d2 = d1; d1 = dist; i1 = kbase + kc + j; }
            else if (dist < d2) { d2 = dist; }
        }
    }

    sd1[q][p] = d1; sd2[q][p] = d2; si1[q][p] = i1;
    __syncthreads();
    if (q == 0) {
        float bd1 = sd1[0][p], bd2 = sd2[0][p];
        int bi = si1[0][p];
#pragma unroll
        for (int j = 1; j < 4; ++j) {
            float a1 = sd1[j][p], a2 = sd2[j][p];
            int ai = si1[j][p];
            if (a1 < bd1) { bd2 = fminf(bd1, a2); bd1 = a1; bi = ai; }
            else { bd2 = fminf(bd2, fminf(a1, a2)); }
        }
        const long n = n0 + p;
        idx[n] = bi;
        if (__fsub_rn(bd2, bd1) <= bd1 * 6.0e-7f) {
            int pos = atomicAdd(flag_count, 1);
            if (pos < MAX_FLAGS) flags[pos] = (int)n;
        }
    }
}

// ---------------------------------------------------------------------------
// exact-dot refine: one block per flagged pixel, 1024 threads = 1 code each.
// (round-4 proven: coalesced wT loads, f64 exact, first-index tie-break)
// ---------------------------------------------------------------------------
__global__ __launch_bounds__(1024)
void k_refine(const float* __restrict__ x, const float* __restrict__ wtr,
              const float* __restrict__ wsq, const float* __restrict__ xsq,
              const int* __restrict__ flags, const int* __restrict__ flag_count,
              int* __restrict__ idx) {
    __shared__ float xsf[DIM];
    __shared__ float rd[1024];
    __shared__ int   ri[1024];
    int nf = *flag_count;
    if (nf > MAX_FLAGS) nf = MAX_FLAGS;
    const int t = threadIdx.x;
    for (int fi = blockIdx.x; fi < nf; fi += gridDim.x) {
        int n = flags[fi];
        int b = n >> 12, hw = n & 4095;
        const float* xp = x + (long)b * DIM * HW + hw;
        __syncthreads();
        if (t < DIM) xsf[t] = xp[(long)t * HW];
        __syncthreads();
        const float s1 = xsq[n];
        double a0 = 0.0, a1 = 0.0, a2 = 0.0, a3 = 0.0;
#pragma unroll 8
        for (int d = 0; d < DIM; d += 4) {
            a0 = fma((double)wtr[(long)(d + 0) * NUM_K + t], (double)xsf[d + 0], a0);
            a1 = fma((double)wtr[(long)(d + 1) * NUM_K + t], (double)xsf[d + 1], a1);
            a2 = fma((double)wtr[(long)(d + 2) * NUM_K + t], (double)xsf[d + 2], a2);
            a3 = fma((double)wtr[(long)(d + 3) * NUM_K + t], (double)xsf[d + 3], a3);
        }
        float dots = (float)((a0 + a1) + (a2 + a3));
        float dk = __fsub_rn(__fadd_rn(s1, wsq[t]), __fmul_rn(2.0f, dots));
        rd[t] = dk; ri[t] = t;
        __syncthreads();
        for (int s = 512; s > 0; s >>= 1) {
            if (t < s) {
                float ra = rd[t + s]; int ia = ri[t + s];
                if (ra < rd[t] || (ra == rd[t] && ia < ri[t])) { rd[t] = ra; ri[t] = ia; }
            }
            __syncthreads();
        }
        if (t == 0) idx[n] = ri[0];
    }
}

// ---------- gather + straight-through + loss ----------
__global__ __launch_bounds__(256, 2)
void k_quant(const float* __restrict__ x, const float* __restrict__ w,
             const int* __restrict__ idx, float* __restrict__ qout,
             float* __restrict__ iout, float* __restrict__ loss) {
    __shared__ float wrow[64 * 257];
    __shared__ int lidx[64];
    __shared__ float part[4];
    const int t = threadIdx.x;
    const long n0 = (long)blockIdx.x * 64;
    const int b = (int)(n0 >> 12), hw0 = (int)(n0 & 4095);

    if (t < 64) lidx[t] = idx[n0 + t];
    __syncthreads();
    for (int i = 0; i < 64; ++i) {
        wrow[i * 257 + t] = w[(long)lidx[i] * DIM + t];
    }
    if (t < 64) iout[n0 + t] = (float)lidx[t];
    __syncthreads();

    const int p = t & 63, cg = t >> 6;
    const float* xb = x + (long)b * DIM * HW + hw0;
    float* qb = qout + (long)b * DIM * HW + hw0;
    float lsum = 0.f;
    for (int i = 0; i < 64; ++i) {
        int c = cg * 64 + i;
        float qv = wrow[p * 257 + c];
        long off = (long)c * HW + p;
        float xv = xb[off];
        float diff = __fsub_rn(qv, xv);
        qb[off] = __fadd_rn(xv, diff);
        lsum = __fmaf_rn(diff, diff, lsum);
    }
#pragma unroll
    for (int off = 32; off; off >>= 1) lsum += __shfl_down(lsum, off);
    if ((t & 63) == 0) part[t >> 6] = lsum;
    __syncthreads();
    if (t == 0) {
        float tot = (part[0] + part[1]) + (part[2] + part[3]);
        atomicAdd(loss, tot * (1.25f / 16777216.f));
    }
}

extern "C" void kernel_launch(void* const* d_in, const int* in_sizes, int n_in,
                              void* d_out, int out_size, void* d_ws, size_t ws_size,
                              hipStream_t stream) {
    const float* x = (const float*)d_in[0];
    const float* w = (const float*)d_in[1];

    float* qout = (float*)d_out;
    float* iout = qout + QELEMS;
    float* loss = iout + NPIX;

    char* wp = (char*)d_ws;
    int*   idx        = (int*)wp;                 wp += (size_t)NPIX * 4;        // 256KB
    float* wsq        = (float*)wp;               wp += (size_t)NUM_K * 4;       // 4KB
    float* xsq        = (float*)wp;               wp += (size_t)NPIX * 4;        // 256KB
    int*   flags      = (int*)wp;                 wp += (size_t)MAX_FLAGS * 4;   // 64KB
    int*   flag_count = (int*)wp;                 wp += 256;
    float* wtr        = (float*)wp;               wp += (size_t)NUM_K * DIM * 4; // 1MB
    short* whi        = (short*)wp;               wp += (size_t)NUM_K * DIM * 2; // 512KB
    short* wlo        = (short*)wp;               wp += (size_t)NUM_K * DIM * 2; // 512KB
    float* pd1        = (float*)wp;               wp += (size_t)8 * NPIX * 4;    // 2MB
    float* pd2        = (float*)wp;               wp += (size_t)8 * NPIX * 4;    // 2MB
    int*   pi1        = (int*)wp;                 wp += (size_t)8 * NPIX * 4;    // 2MB
    size_t need = (size_t)(wp - (char*)d_ws);

    hipMemsetAsync(loss, 0, sizeof(float), stream);
    hipMemsetAsync(flag_count, 0, sizeof(int), stream);

    k_wsq<<<4, 256, 0, stream>>>(w, wsq);
    k_xsq<<<NPIX / 256, 256, 0, stream>>>(x, xsq);
    k_wtrans<<<DIM, 1024, 0, stream>>>(w, wtr);

    if (ws_size >= need) {
        k_wfrag<<<128, 256, 0, stream>>>(w, whi, wlo);
        k_argmin_mfma<<<4096, 256, 0, stream>>>(x, whi, wlo, wsq, xsq, pd1, pd2, pi1);
        k_combine<<<NPIX / 256, 256, 0, stream>>>(pd1, pd2, pi1, idx, flags, flag_count);
    } else {
        k_argmin_valu<<<NPIX / 64, 256, 0, stream>>>(x, w, wsq, xsq, idx, flags, flag_count);
    }
    k_refine<<<2048, 1024, 0, stream>>>(x, wtr, wsq, xsq, flags, flag_count, idx);
    k_quant<<<NPIX / 64, 256, 0, stream>>>(x, w, idx, qout, iout, loss);
}

// Round 7
// 326.069 us; speedup vs baseline: 2.4658x; 1.0804x over previous
//
#include <hip/hip_runtime.h>
#include <math.h>

#define NUM_K 1024
#define DIM 256
#define HW 4096          // 64*64
#define NPIX 65536       // 16*4096
#define QELEMS 16777216  // 16*256*4096
#define MAX_FLAGS 16384

typedef short bf16x8 __attribute__((ext_vector_type(8)));
typedef float f32x4 __attribute__((ext_vector_type(4)));

__device__ __forceinline__ unsigned short f32_to_bf16_rne(float f) {
    unsigned int u = __float_as_uint(f);
    unsigned int r = u + 0x7FFFu + ((u >> 16) & 1u);
    return (unsigned short)(r >> 16);
}
__device__ __forceinline__ float bf16_to_f32(unsigned short h) {
    return __uint_as_float(((unsigned int)h) << 16);
}

// ---------------------------------------------------------------------------
// numpy-replicated f32 sum of squares over 256 elements (pairwise SIMD tree).
// (validated bit-exact vs harness numpy in rounds 2-6)
// ---------------------------------------------------------------------------
__device__ __forceinline__ float np_sumsq_256(const float* __restrict__ p, long stride) {
    float blk0 = 0.f, blk1 = 0.f;
#pragma unroll
    for (int h = 0; h < 2; ++h) {
        const float* base = p + (long)h * 128 * stride;
        float s[16];
#pragma unroll
        for (int L = 0; L < 16; ++L) {
            float a0 = base[(long)(L)       * stride]; a0 = __fmul_rn(a0, a0);
            float a1 = base[(long)(16 + L)  * stride]; a1 = __fmul_rn(a1, a1);
            float a2 = base[(long)(32 + L)  * stride]; a2 = __fmul_rn(a2, a2);
            float a3 = base[(long)(48 + L)  * stride]; a3 = __fmul_rn(a3, a3);
            float a4 = base[(long)(64 + L)  * stride]; a4 = __fmul_rn(a4, a4);
            float a5 = base[(long)(80 + L)  * stride]; a5 = __fmul_rn(a5, a5);
            float a6 = base[(long)(96 + L)  * stride]; a6 = __fmul_rn(a6, a6);
            float a7 = base[(long)(112 + L) * stride]; a7 = __fmul_rn(a7, a7);
            float t1 = __fadd_rn(a0, a1);
            float t2 = __fadd_rn(a2, a3);
            float t3 = __fadd_rn(a4, a5);
            float t4 = __fadd_rn(a6, a7);
            s[L] = __fadd_rn(__fadd_rn(t1, t2), __fadd_rn(t3, t4));
        }
        float c0 = __fadd_rn(s[0], s[8]);
        float c1 = __fadd_rn(s[1], s[9]);
        float c2 = __fadd_rn(s[2], s[10]);
        float c3 = __fadd_rn(s[3], s[11]);
        float c4 = __fadd_rn(s[4], s[12]);
        float c5 = __fadd_rn(s[5], s[13]);
        float c6 = __fadd_rn(s[6], s[14]);
        float c7 = __fadd_rn(s[7], s[15]);
        float d0 = __fadd_rn(c0, c4);
        float d1 = __fadd_rn(c1, c5);
        float d2 = __fadd_rn(c2, c6);
        float d3 = __fadd_rn(c3, c7);
        float e0 = __fadd_rn(d0, d2);
        float e1 = __fadd_rn(d1, d3);
        float r  = __fadd_rn(e0, e1);
        if (h == 0) blk0 = r; else blk1 = r;
    }
    return __fadd_rn(blk0, blk1);
}

__global__ __launch_bounds__(256) void k_wsq(const float* __restrict__ w, float* __restrict__ wsq) {
    int k = blockIdx.x * 256 + threadIdx.x;
    if (k < NUM_K) wsq[k] = np_sumsq_256(w + (long)k * DIM, 1);
}

__global__ __launch_bounds__(256) void k_xsq(const float* __restrict__ x, float* __restrict__ xsq) {
    int n = blockIdx.x * 256 + threadIdx.x;
    int b = n >> 12, hw = n & 4095;
    xsq[n] = np_sumsq_256(x + (long)b * DIM * HW + hw, HW);
}

// ---------- w transpose: wtr[d][k] = w[k][d], for coalesced refine loads ----------
__global__ __launch_bounds__(1024)
void k_wtrans(const float* __restrict__ w, float* __restrict__ wtr) {
    int d = blockIdx.x;
    int k = threadIdx.x;
    wtr[(long)d * NUM_K + k] = w[(long)k * DIM + d];
}

// ---------------------------------------------------------------------------
// w -> frag-major bf16 (hi only) for B-frag of mfma_f32_16x16x32_bf16.
// lane fl: col(code-in-tile)=fl&15, k = 8*(fl>>4)+j.
// addr = ((ctile*8 + ks)*64 + fl)*8 + j ; ctile=code>>4, ks=d>>5.
// ---------------------------------------------------------------------------
__global__ __launch_bounds__(256)
void k_wfrag(const float* __restrict__ w, short* __restrict__ whi) {
    int id = blockIdx.x * 256 + threadIdx.x;   // 32768 = 1024 codes * 32 chunks
    int code = id >> 5;
    int c = id & 31;                            // d-chunk of 8: d = c*8+j
    const float* src = w + (long)code * DIM + c * 8;
    bf16x8 vh;
#pragma unroll
    for (int j = 0; j < 8; ++j) vh[j] = (short)f32_to_bf16_rne(src[j]);
    int fl = ((c & 3) << 4) | (code & 15);
    long addr = ((((long)(code >> 4) * 8 + (c >> 2)) * 64 + fl) * 8);
    *(bf16x8*)(whi + addr) = vh;
}

// ---------------------------------------------------------------------------
// MFMA argmin v7: round-4 geometry (64 px x 512 codes, 4 waves, 256 thr;
// wave = 64px x 128 codes, acc[4][8]) + 2-product split (A hi+lo x B hi) +
// depth-4 software-pipelined B ring over the flattened (ks,n) space.
// Per-wave partials (d1,d2,i1) -> k_combine (proven path).
// ---------------------------------------------------------------------------
#define A_SLOT(ks,m,fl) ((((ks)*4+(m))*64+(fl))*8)

__global__ __launch_bounds__(256, 2)
void k_argmin_mfma(const float* __restrict__ x,
                   const short* __restrict__ whi,
                   const float* __restrict__ wsq, const float* __restrict__ xsq,
                   float* __restrict__ pd1, float* __restrict__ pd2, int* __restrict__ pi1) {
    __shared__ short ahi[8 * 4 * 64 * 8];   // 32KB [ks][m][fl][j]
    __shared__ short alo[8 * 4 * 64 * 8];   // 32KB

    const int t = threadIdx.x;
    const int lane = t & 63;
    const int q = t >> 6;                    // wave id 0..3
    const int tile = blockIdx.x >> 1;        // 1024 pixel tiles of 64
    const int slice = blockIdx.x & 1;        // code slice of 512

    const int b = tile >> 6;
    const int hw0 = (tile & 63) * 64;
    const float* xb = x + (long)b * (DIM * HW) + hw0 + lane;

    // ---- stage A (hi+lo) once: thread handles px=lane, chunks c=q*8..q*8+7 ----
#pragma unroll
    for (int i = 0; i < 8; ++i) {
        int c = q * 8 + i;
        float v[8];
#pragma unroll
        for (int jj = 0; jj < 8; ++jj) v[jj] = xb[(long)(c * 8 + jj) * HW];
        bf16x8 vh, vl;
#pragma unroll
        for (int jj = 0; jj < 8; ++jj) {
            unsigned short hh = f32_to_bf16_rne(v[jj]);
            float r = __fsub_rn(v[jj], bf16_to_f32(hh));
            vh[jj] = (short)hh;
            vl[jj] = (short)f32_to_bf16_rne(r);
        }
        int slot = A_SLOT(c >> 2, lane >> 4, ((c & 3) << 4) | (lane & 15));
        *(bf16x8*)(ahi + slot) = vh;
        *(bf16x8*)(alo + slot) = vl;
    }
    __syncthreads();

    const int ct0 = slice * 32 + q * 8;      // this wave's 16-code-tile base
    f32x4 acc[4][8];
#pragma unroll
    for (int m = 0; m < 4; ++m)
#pragma unroll
        for (int n = 0; n < 8; ++n) acc[m][n] = (f32x4){0.f, 0.f, 0.f, 0.f};

    // flattened i = ks*8 + n, B ring depth 4 (fully unrolled -> static regs)
#define BADDR(i) ((((long)(ct0 + ((i) & 7)) * 8 + ((i) >> 3)) * 64 + lane) * 8)
    bf16x8 bring[4];
#pragma unroll
    for (int i = 0; i < 4; ++i) bring[i] = *(const bf16x8*)(whi + BADDR(i));

    bf16x8 ah[4], al[4];
#pragma unroll
    for (int i = 0; i < 64; ++i) {
        const int ks = i >> 3;
        const int n = i & 7;
        if (n == 0) {
#pragma unroll
            for (int m = 0; m < 4; ++m) {
                ah[m] = *(const bf16x8*)(ahi + A_SLOT(ks, m, lane));
                al[m] = *(const bf16x8*)(alo + A_SLOT(ks, m, lane));
            }
        }
        bf16x8 bcur = bring[i & 3];
        if (i + 4 < 64) bring[i & 3] = *(const bf16x8*)(whi + BADDR(i + 4));
#pragma unroll
        for (int m = 0; m < 4; ++m) {
            acc[m][n] = __builtin_amdgcn_mfma_f32_16x16x32_bf16(ah[m], bcur, acc[m][n], 0, 0, 0);
            acc[m][n] = __builtin_amdgcn_mfma_f32_16x16x32_bf16(al[m], bcur, acc[m][n], 0, 0, 0);
        }
    }
#undef BADDR

    // ---- epilogue: dist = fl(fl(s1+wsq) - 2*dot); per-lane (d1,d2,i1) ----
    const long px0 = (long)tile * 64;
    const int rbase = (lane >> 4) * 4;
    float s1v[4][4];
#pragma unroll
    for (int m = 0; m < 4; ++m)
#pragma unroll
        for (int r = 0; r < 4; ++r) s1v[m][r] = xsq[px0 + 16 * m + rbase + r];

    float bd1[4][4], bd2[4][4];
    int bi1[4][4];
#pragma unroll
    for (int m = 0; m < 4; ++m)
#pragma unroll
        for (int r = 0; r < 4; ++r) { bd1[m][r] = INFINITY; bd2[m][r] = INFINITY; bi1[m][r] = 0; }

#pragma unroll
    for (int n = 0; n < 8; ++n) {
        int code = (ct0 + n) * 16 + (lane & 15);
        float wq = wsq[code];
#pragma unroll
        for (int m = 0; m < 4; ++m) {
#pragma unroll
            for (int r = 0; r < 4; ++r) {
                float tt = __fadd_rn(s1v[m][r], wq);
                float dist = __fmaf_rn(-2.0f, acc[m][n][r], tt);
                bool c1 = dist < bd1[m][r];
                bool c2 = dist < bd2[m][r];
                bd2[m][r] = c1 ? bd1[m][r] : (c2 ? dist : bd2[m][r]);
                bd1[m][r] = c1 ? dist : bd1[m][r];
                bi1[m][r] = c1 ? code : bi1[m][r];
            }
        }
    }

    // butterfly across the 16 lanes holding different codes
#pragma unroll
    for (int step = 1; step < 16; step <<= 1) {
#pragma unroll
        for (int m = 0; m < 4; ++m) {
#pragma unroll
            for (int r = 0; r < 4; ++r) {
                float od1 = __shfl_xor(bd1[m][r], step);
                float od2 = __shfl_xor(bd2[m][r], step);
                int   oi  = __shfl_xor(bi1[m][r], step);
                bool take = (od1 < bd1[m][r]) || ((od1 == bd1[m][r]) && (oi < bi1[m][r]));
                float nd2 = fminf(fmaxf(od1, bd1[m][r]), fminf(od2, bd2[m][r]));
                bd1[m][r] = take ? od1 : bd1[m][r];
                bi1[m][r] = take ? oi : bi1[m][r];
                bd2[m][r] = nd2;
            }
        }
    }

    if ((lane & 15) == 0) {
        const long ws_id = slice * 4 + q;    // ascending code order
#pragma unroll
        for (int m = 0; m < 4; ++m) {
#pragma unroll
            for (int r = 0; r < 4; ++r) {
                long pix = px0 + 16 * m + rbase + r;
                pd1[ws_id * NPIX + pix] = bd1[m][r];
                pd2[ws_id * NPIX + pix] = bd2[m][r];
                pi1[ws_id * NPIX + pix] = bi1[m][r];
            }
        }
    }
}

// ---------- combine 8 code-slice partials, flag near-ties ----------
// margin widened to d1*1e-6: covers f32-grid ties (~5 ulp) AND the 2-product
// bf16-split noise (std ~4e-5, margin ~= 4.5 sigma of err-diff).
__global__ __launch_bounds__(256)
void k_combine(const float* __restrict__ pd1, const float* __restrict__ pd2,
               const int* __restrict__ pi1, int* __restrict__ idx,
               int* __restrict__ flags, int* __restrict__ flag_count) {
    int n = blockIdx.x * 256 + threadIdx.x;
    float d1 = pd1[n], d2 = pd2[n];
    int i1 = pi1[n];
#pragma unroll
    for (int s = 1; s < 8; ++s) {
        float a1 = pd1[(long)s * NPIX + n];
        float a2 = pd2[(long)s * NPIX + n];
        int   ai = pi1[(long)s * NPIX + n];
        bool take = (a1 < d1) || ((a1 == d1) && (ai < i1));
        float nd2 = fminf(fmaxf(a1, d1), fminf(a2, d2));
        d1 = take ? a1 : d1;
        i1 = take ? ai : i1;
        d2 = nd2;
    }
    idx[n] = i1;
    if (__fsub_rn(d2, d1) <= d1 * 1.0e-6f) {
        int pos = atomicAdd(flag_count, 1);
        if (pos < MAX_FLAGS) flags[pos] = n;
    }
}

// ---------- fallback VALU argmin (round-2 proven path) ----------
__global__ __launch_bounds__(256, 2)
void k_argmin_valu(const float* __restrict__ x, const float* __restrict__ w,
                   const float* __restrict__ wsq, const float* __restrict__ xsq,
                   int* __restrict__ idx, int* __restrict__ flags, int* __restrict__ flag_count) {
    __shared__ float xs[64 * 257];
    __shared__ float sd1[4][64];
    __shared__ float sd2[4][64];
    __shared__ int   si1[4][64];

    const int t = threadIdx.x;
    const int p = t & 63;
    const int q = t >> 6;
    const long n0 = (long)blockIdx.x * 64;
    const int b = (int)(n0 >> 12);
    const int hw0 = (int)(n0 & 4095);
    const float* xb = x + (long)b * DIM * HW + hw0;

    for (int i = 0; i < 64; ++i) {
        int c = q * 64 + i;
        xs[p * 257 + c] = xb[(long)c * HW + p];
    }
    __syncthreads();

    const float* xrow = xs + p * 257;
    const float s1 = xsq[n0 + p];
    float d1 = INFINITY, d2 = INFINITY;
    int i1 = 0;
    const int kbase = q * 256;
    const float* wq = w + (long)kbase * DIM;
    const float* wsq_q = wsq + kbase;

    for (int kc = 0; kc < 256; kc += 8) {
        float acc[8] = {0.f, 0.f, 0.f, 0.f, 0.f, 0.f, 0.f, 0.f};
        const float* w0 = wq + (long)kc * DIM;
#pragma unroll 2
        for (int d = 0; d < DIM; d += 4) {
            float x0 = xrow[d + 0];
            float x1 = xrow[d + 1];
            float x2 = xrow[d + 2];
            float x3 = xrow[d + 3];
#pragma unroll
            for (int j = 0; j < 8; ++j) {
                const float4 wv = *reinterpret_cast<const float4*>(w0 + j * DIM + d);
                acc[j] = __fmaf_rn(x0, wv.x, acc[j]);
                acc[j] = __fmaf_rn(x1, wv.y, acc[j]);
                acc[j] = __fmaf_rn(x2, wv.z, acc[j]);
                acc[j] = __fmaf_rn(x3, wv.w, acc[j]);
            }
        }
#pragma unroll
        for (int j = 0; j < 8; ++j) {
            float tk = __fadd_rn(s1, wsq_q[kc + j]);
            float dist = __fsub_rn(tk, __fmul_rn(2.0f, acc[j]));
            if (dist < d1) { d2 = d1; d1 = dist; i1 = kbase + kc + j; }
            else if (dist < d2) { d2 = dist; }
        }
    }

    sd1[q][p] = d1; sd2[q][p] = d2; si1[q][p] = i1;
    __syncthreads();
    if (q == 0) {
        float bd1 = sd1[0][p], bd2 = sd2[0][p];
        int bi = si1[0][p];
#pragma unroll
        for (int j = 1; j < 4; ++j) {
            float a1 = sd1[j][p], a2 = sd2[j][p];
            int ai = si1[j][p];
            if (a1 < bd1) { bd2 = fminf(bd1, a2); bd1 = a1; bi = ai; }
            else { bd2 = fminf(bd2, fminf(a1, a2)); }
        }
        const long n = n0 + p;
        idx[n] = bi;
        if (__fsub_rn(bd2, bd1) <= bd1 * 6.0e-7f) {
            int pos = atomicAdd(flag_count, 1);
            if (pos < MAX_FLAGS) flags[pos] = (int)n;
        }
    }
}

// ---------------------------------------------------------------------------
// exact-dot refine: one block per flagged pixel, 1024 threads = 1 code each.
// (round-4 proven: coalesced wT loads, f64 exact, first-index tie-break)
// ---------------------------------------------------------------------------
__global__ __launch_bounds__(1024)
void k_refine(const float* __restrict__ x, const float* __restrict__ wtr,
              const float* __restrict__ wsq, const float* __restrict__ xsq,
              const int* __restrict__ flags, const int* __restrict__ flag_count,
              int* __restrict__ idx) {
    __shared__ float xsf[DIM];
    __shared__ float rd[1024];
    __shared__ int   ri[1024];
    int nf = *flag_count;
    if (nf > MAX_FLAGS) nf = MAX_FLAGS;
    const int t = threadIdx.x;
    for (int fi = blockIdx.x; fi < nf; fi += gridDim.x) {
        int n = flags[fi];
        int b = n >> 12, hw = n & 4095;
        const float* xp = x + (long)b * DIM * HW + hw;
        __syncthreads();
        if (t < DIM) xsf[t] = xp[(long)t * HW];
        __syncthreads();
        const float s1 = xsq[n];
        double a0 = 0.0, a1 = 0.0, a2 = 0.0, a3 = 0.0;
#pragma unroll 8
        for (int d = 0; d < DIM; d += 4) {
            a0 = fma((double)wtr[(long)(d + 0) * NUM_K + t], (double)xsf[d + 0], a0);
            a1 = fma((double)wtr[(long)(d + 1) * NUM_K + t], (double)xsf[d + 1], a1);
            a2 = fma((double)wtr[(long)(d + 2) * NUM_K + t], (double)xsf[d + 2], a2);
            a3 = fma((double)wtr[(long)(d + 3) * NUM_K + t], (double)xsf[d + 3], a3);
        }
        float dots = (float)((a0 + a1) + (a2 + a3));
        float dk = __fsub_rn(__fadd_rn(s1, wsq[t]), __fmul_rn(2.0f, dots));
        rd[t] = dk; ri[t] = t;
        __syncthreads();
        for (int s = 512; s > 0; s >>= 1) {
            if (t < s) {
                float ra = rd[t + s]; int ia = ri[t + s];
                if (ra < rd[t] || (ra == rd[t] && ia < ri[t])) { rd[t] = ra; ri[t] = ia; }
            }
            __syncthreads();
        }
        if (t == 0) idx[n] = ri[0];
    }
}

// ---------- gather + straight-through + loss ----------
__global__ __launch_bounds__(256, 2)
void k_quant(const float* __restrict__ x, const float* __restrict__ w,
             const int* __restrict__ idx, float* __restrict__ qout,
             float* __restrict__ iout, float* __restrict__ loss) {
    __shared__ float wrow[64 * 257];
    __shared__ int lidx[64];
    __shared__ float part[4];
    const int t = threadIdx.x;
    const long n0 = (long)blockIdx.x * 64;
    const int b = (int)(n0 >> 12), hw0 = (int)(n0 & 4095);

    if (t < 64) lidx[t] = idx[n0 + t];
    __syncthreads();
    for (int i = 0; i < 64; ++i) {
        wrow[i * 257 + t] = w[(long)lidx[i] * DIM + t];
    }
    if (t < 64) iout[n0 + t] = (float)lidx[t];
    __syncthreads();

    const int p = t & 63, cg = t >> 6;
    const float* xb = x + (long)b * DIM * HW + hw0;
    float* qb = qout + (long)b * DIM * HW + hw0;
    float lsum = 0.f;
    for (int i = 0; i < 64; ++i) {
        int c = cg * 64 + i;
        float qv = wrow[p * 257 + c];
        long off = (long)c * HW + p;
        float xv = xb[off];
        float diff = __fsub_rn(qv, xv);
        qb[off] = __fadd_rn(xv, diff);
        lsum = __fmaf_rn(diff, diff, lsum);
    }
#pragma unroll
    for (int off = 32; off; off >>= 1) lsum += __shfl_down(lsum, off);
    if ((t & 63) == 0) part[t >> 6] = lsum;
    __syncthreads();
    if (t == 0) {
        float tot = (part[0] + part[1]) + (part[2] + part[3]);
        atomicAdd(loss, tot * (1.25f / 16777216.f));
    }
}

extern "C" void kernel_launch(void* const* d_in, const int* in_sizes, int n_in,
                              void* d_out, int out_size, void* d_ws, size_t ws_size,
                              hipStream_t stream) {
    const float* x = (const float*)d_in[0];
    const float* w = (const float*)d_in[1];

    float* qout = (float*)d_out;
    float* iout = qout + QELEMS;
    float* loss = iout + NPIX;

    char* wp = (char*)d_ws;
    int*   idx        = (int*)wp;                 wp += (size_t)NPIX * 4;        // 256KB
    float* wsq        = (float*)wp;               wp += (size_t)NUM_K * 4;       // 4KB
    float* xsq        = (float*)wp;               wp += (size_t)NPIX * 4;        // 256KB
    int*   flags      = (int*)wp;                 wp += (size_t)MAX_FLAGS * 4;   // 64KB
    int*   flag_count = (int*)wp;                 wp += 256;
    float* wtr        = (float*)wp;               wp += (size_t)NUM_K * DIM * 4; // 1MB
    short* whi        = (short*)wp;               wp += (size_t)NUM_K * DIM * 2; // 512KB
    float* pd1        = (float*)wp;               wp += (size_t)8 * NPIX * 4;    // 2MB
    float* pd2        = (float*)wp;               wp += (size_t)8 * NPIX * 4;    // 2MB
    int*   pi1        = (int*)wp;                 wp += (size_t)8 * NPIX * 4;    // 2MB
    size_t need = (size_t)(wp - (char*)d_ws);

    hipMemsetAsync(loss, 0, sizeof(float), stream);
    hipMemsetAsync(flag_count, 0, sizeof(int), stream);

    k_wsq<<<4, 256, 0, stream>>>(w, wsq);
    k_xsq<<<NPIX / 256, 256, 0, stream>>>(x, xsq);
    k_wtrans<<<DIM, 1024, 0, stream>>>(w, wtr);

    if (ws_size >= need) {
        k_wfrag<<<128, 256, 0, stream>>>(w, whi);
        k_argmin_mfma<<<2048, 256, 0, stream>>>(x, whi, wsq, xsq, pd1, pd2, pi1);
        k_combine<<<NPIX / 256, 256, 0, stream>>>(pd1, pd2, pi1, idx, flags, flag_count);
    } else {
        k_argmin_valu<<<NPIX / 64, 256, 0, stream>>>(x, w, wsq, xsq, idx, flags, flag_count);
    }
    k_refine<<<2048, 1024, 0, stream>>>(x, wtr, wsq, xsq, flags, flag_count, idx);
    k_quant<<<NPIX / 64, 256, 0, stream>>>(x, w, idx, qout, iout, loss);
}

// Round 8
// 269.164 us; speedup vs baseline: 2.9871x; 1.2114x over previous
//
#include <hip/hip_runtime.h>
#include <math.h>

#define NUM_K 1024
#define DIM 256
#define HW 4096          // 64*64
#define NPIX 65536       // 16*4096
#define QELEMS 16777216  // 16*256*4096
#define MAX_FLAGS 16384

typedef short bf16x8 __attribute__((ext_vector_type(8)));
typedef float f32x4 __attribute__((ext_vector_type(4)));

__device__ __forceinline__ unsigned short f32_to_bf16_rne(float f) {
    unsigned int u = __float_as_uint(f);
    unsigned int r = u + 0x7FFFu + ((u >> 16) & 1u);
    return (unsigned short)(r >> 16);
}
__device__ __forceinline__ float bf16_to_f32(unsigned short h) {
    return __uint_as_float(((unsigned int)h) << 16);
}

// ---------------------------------------------------------------------------
// numpy-replicated f32 sum of squares over 256 elements (pairwise SIMD tree).
// (validated bit-exact vs harness numpy in rounds 2-7)
// ---------------------------------------------------------------------------
__device__ __forceinline__ float np_sumsq_256(const float* __restrict__ p, long stride) {
    float blk0 = 0.f, blk1 = 0.f;
#pragma unroll
    for (int h = 0; h < 2; ++h) {
        const float* base = p + (long)h * 128 * stride;
        float s[16];
#pragma unroll
        for (int L = 0; L < 16; ++L) {
            float a0 = base[(long)(L)       * stride]; a0 = __fmul_rn(a0, a0);
            float a1 = base[(long)(16 + L)  * stride]; a1 = __fmul_rn(a1, a1);
            float a2 = base[(long)(32 + L)  * stride]; a2 = __fmul_rn(a2, a2);
            float a3 = base[(long)(48 + L)  * stride]; a3 = __fmul_rn(a3, a3);
            float a4 = base[(long)(64 + L)  * stride]; a4 = __fmul_rn(a4, a4);
            float a5 = base[(long)(80 + L)  * stride]; a5 = __fmul_rn(a5, a5);
            float a6 = base[(long)(96 + L)  * stride]; a6 = __fmul_rn(a6, a6);
            float a7 = base[(long)(112 + L) * stride]; a7 = __fmul_rn(a7, a7);
            float t1 = __fadd_rn(a0, a1);
            float t2 = __fadd_rn(a2, a3);
            float t3 = __fadd_rn(a4, a5);
            float t4 = __fadd_rn(a6, a7);
            s[L] = __fadd_rn(__fadd_rn(t1, t2), __fadd_rn(t3, t4));
        }
        float c0 = __fadd_rn(s[0], s[8]);
        float c1 = __fadd_rn(s[1], s[9]);
        float c2 = __fadd_rn(s[2], s[10]);
        float c3 = __fadd_rn(s[3], s[11]);
        float c4 = __fadd_rn(s[4], s[12]);
        float c5 = __fadd_rn(s[5], s[13]);
        float c6 = __fadd_rn(s[6], s[14]);
        float c7 = __fadd_rn(s[7], s[15]);
        float d0 = __fadd_rn(c0, c4);
        float d1 = __fadd_rn(c1, c5);
        float d2 = __fadd_rn(c2, c6);
        float d3 = __fadd_rn(c3, c7);
        float e0 = __fadd_rn(d0, d2);
        float e1 = __fadd_rn(d1, d3);
        float r  = __fadd_rn(e0, e1);
        if (h == 0) blk0 = r; else blk1 = r;
    }
    return __fadd_rn(blk0, blk1);
}

__global__ __launch_bounds__(256) void k_wsq(const float* __restrict__ w, float* __restrict__ wsq) {
    int k = blockIdx.x * 256 + threadIdx.x;
    if (k < NUM_K) wsq[k] = np_sumsq_256(w + (long)k * DIM, 1);
}

__global__ __launch_bounds__(256) void k_xsq(const float* __restrict__ x, float* __restrict__ xsq) {
    int n = blockIdx.x * 256 + threadIdx.x;
    int b = n >> 12, hw = n & 4095;
    xsq[n] = np_sumsq_256(x + (long)b * DIM * HW + hw, HW);
}

// ---------- w transpose: wtr[d][k] = w[k][d], for coalesced refine loads ----------
__global__ __launch_bounds__(1024)
void k_wtrans(const float* __restrict__ w, float* __restrict__ wtr) {
    int d = blockIdx.x;
    int k = threadIdx.x;
    wtr[(long)d * NUM_K + k] = w[(long)k * DIM + d];
}

// ---------------------------------------------------------------------------
// w -> frag-major bf16 (hi only) for B-frag of mfma_f32_16x16x32_bf16.
// ---------------------------------------------------------------------------
__global__ __launch_bounds__(256)
void k_wfrag(const float* __restrict__ w, short* __restrict__ whi) {
    int id = blockIdx.x * 256 + threadIdx.x;   // 32768 = 1024 codes * 32 chunks
    int code = id >> 5;
    int c = id & 31;                            // d-chunk of 8: d = c*8+j
    const float* src = w + (long)code * DIM + c * 8;
    bf16x8 vh;
#pragma unroll
    for (int j = 0; j < 8; ++j) vh[j] = (short)f32_to_bf16_rne(src[j]);
    int fl = ((c & 3) << 4) | (code & 15);
    long addr = ((((long)(code >> 4) * 8 + (c >> 2)) * 64 + fl) * 8);
    *(bf16x8*)(whi + addr) = vh;
}

// ---------------------------------------------------------------------------
// MFMA argmin v7 (round-7 proven): 64 px x 512 codes, 4 waves; 2-product
// split (A hi+lo x B hi); depth-4 B ring; partials -> k_combine.
// ---------------------------------------------------------------------------
#define A_SLOT(ks,m,fl) ((((ks)*4+(m))*64+(fl))*8)

__global__ __launch_bounds__(256, 2)
void k_argmin_mfma(const float* __restrict__ x,
                   const short* __restrict__ whi,
                   const float* __restrict__ wsq, const float* __restrict__ xsq,
                   float* __restrict__ pd1, float* __restrict__ pd2, int* __restrict__ pi1) {
    __shared__ short ahi[8 * 4 * 64 * 8];   // 32KB [ks][m][fl][j]
    __shared__ short alo[8 * 4 * 64 * 8];   // 32KB

    const int t = threadIdx.x;
    const int lane = t & 63;
    const int q = t >> 6;                    // wave id 0..3
    const int tile = blockIdx.x >> 1;        // 1024 pixel tiles of 64
    const int slice = blockIdx.x & 1;        // code slice of 512

    const int b = tile >> 6;
    const int hw0 = (tile & 63) * 64;
    const float* xb = x + (long)b * (DIM * HW) + hw0 + lane;

#pragma unroll
    for (int i = 0; i < 8; ++i) {
        int c = q * 8 + i;
        float v[8];
#pragma unroll
        for (int jj = 0; jj < 8; ++jj) v[jj] = xb[(long)(c * 8 + jj) * HW];
        bf16x8 vh, vl;
#pragma unroll
        for (int jj = 0; jj < 8; ++jj) {
            unsigned short hh = f32_to_bf16_rne(v[jj]);
            float r = __fsub_rn(v[jj], bf16_to_f32(hh));
            vh[jj] = (short)hh;
            vl[jj] = (short)f32_to_bf16_rne(r);
        }
        int slot = A_SLOT(c >> 2, lane >> 4, ((c & 3) << 4) | (lane & 15));
        *(bf16x8*)(ahi + slot) = vh;
        *(bf16x8*)(alo + slot) = vl;
    }
    __syncthreads();

    const int ct0 = slice * 32 + q * 8;      // this wave's 16-code-tile base
    f32x4 acc[4][8];
#pragma unroll
    for (int m = 0; m < 4; ++m)
#pragma unroll
        for (int n = 0; n < 8; ++n) acc[m][n] = (f32x4){0.f, 0.f, 0.f, 0.f};

#define BADDR(i) ((((long)(ct0 + ((i) & 7)) * 8 + ((i) >> 3)) * 64 + lane) * 8)
    bf16x8 bring[4];
#pragma unroll
    for (int i = 0; i < 4; ++i) bring[i] = *(const bf16x8*)(whi + BADDR(i));

    bf16x8 ah[4], al[4];
#pragma unroll
    for (int i = 0; i < 64; ++i) {
        const int ks = i >> 3;
        const int n = i & 7;
        if (n == 0) {
#pragma unroll
            for (int m = 0; m < 4; ++m) {
                ah[m] = *(const bf16x8*)(ahi + A_SLOT(ks, m, lane));
                al[m] = *(const bf16x8*)(alo + A_SLOT(ks, m, lane));
            }
        }
        bf16x8 bcur = bring[i & 3];
        if (i + 4 < 64) bring[i & 3] = *(const bf16x8*)(whi + BADDR(i + 4));
#pragma unroll
        for (int m = 0; m < 4; ++m) {
            acc[m][n] = __builtin_amdgcn_mfma_f32_16x16x32_bf16(ah[m], bcur, acc[m][n], 0, 0, 0);
            acc[m][n] = __builtin_amdgcn_mfma_f32_16x16x32_bf16(al[m], bcur, acc[m][n], 0, 0, 0);
        }
    }
#undef BADDR

    const long px0 = (long)tile * 64;
    const int rbase = (lane >> 4) * 4;
    float s1v[4][4];
#pragma unroll
    for (int m = 0; m < 4; ++m)
#pragma unroll
        for (int r = 0; r < 4; ++r) s1v[m][r] = xsq[px0 + 16 * m + rbase + r];

    float bd1[4][4], bd2[4][4];
    int bi1[4][4];
#pragma unroll
    for (int m = 0; m < 4; ++m)
#pragma unroll
        for (int r = 0; r < 4; ++r) { bd1[m][r] = INFINITY; bd2[m][r] = INFINITY; bi1[m][r] = 0; }

#pragma unroll
    for (int n = 0; n < 8; ++n) {
        int code = (ct0 + n) * 16 + (lane & 15);
        float wq = wsq[code];
#pragma unroll
        for (int m = 0; m < 4; ++m) {
#pragma unroll
            for (int r = 0; r < 4; ++r) {
                float tt = __fadd_rn(s1v[m][r], wq);
                float dist = __fmaf_rn(-2.0f, acc[m][n][r], tt);
                bool c1 = dist < bd1[m][r];
                bool c2 = dist < bd2[m][r];
                bd2[m][r] = c1 ? bd1[m][r] : (c2 ? dist : bd2[m][r]);
                bd1[m][r] = c1 ? dist : bd1[m][r];
                bi1[m][r] = c1 ? code : bi1[m][r];
            }
        }
    }

#pragma unroll
    for (int step = 1; step < 16; step <<= 1) {
#pragma unroll
        for (int m = 0; m < 4; ++m) {
#pragma unroll
            for (int r = 0; r < 4; ++r) {
                float od1 = __shfl_xor(bd1[m][r], step);
                float od2 = __shfl_xor(bd2[m][r], step);
                int   oi  = __shfl_xor(bi1[m][r], step);
                bool take = (od1 < bd1[m][r]) || ((od1 == bd1[m][r]) && (oi < bi1[m][r]));
                float nd2 = fminf(fmaxf(od1, bd1[m][r]), fminf(od2, bd2[m][r]));
                bd1[m][r] = take ? od1 : bd1[m][r];
                bi1[m][r] = take ? oi : bi1[m][r];
                bd2[m][r] = nd2;
            }
        }
    }

    if ((lane & 15) == 0) {
        const long ws_id = slice * 4 + q;    // ascending code order
#pragma unroll
        for (int m = 0; m < 4; ++m) {
#pragma unroll
            for (int r = 0; r < 4; ++r) {
                long pix = px0 + 16 * m + rbase + r;
                pd1[ws_id * NPIX + pix] = bd1[m][r];
                pd2[ws_id * NPIX + pix] = bd2[m][r];
                pi1[ws_id * NPIX + pix] = bi1[m][r];
            }
        }
    }
}

// ---------- combine 8 code-slice partials, flag near-ties ----------
__global__ __launch_bounds__(256)
void k_combine(const float* __restrict__ pd1, const float* __restrict__ pd2,
               const int* __restrict__ pi1, int* __restrict__ idx,
               int* __restrict__ flags, int* __restrict__ flag_count) {
    int n = blockIdx.x * 256 + threadIdx.x;
    float d1 = pd1[n], d2 = pd2[n];
    int i1 = pi1[n];
#pragma unroll
    for (int s = 1; s < 8; ++s) {
        float a1 = pd1[(long)s * NPIX + n];
        float a2 = pd2[(long)s * NPIX + n];
        int   ai = pi1[(long)s * NPIX + n];
        bool take = (a1 < d1) || ((a1 == d1) && (ai < i1));
        float nd2 = fminf(fmaxf(a1, d1), fminf(a2, d2));
        d1 = take ? a1 : d1;
        i1 = take ? ai : i1;
        d2 = nd2;
    }
    idx[n] = i1;
    if (__fsub_rn(d2, d1) <= d1 * 1.0e-6f) {
        int pos = atomicAdd(flag_count, 1);
        if (pos < MAX_FLAGS) flags[pos] = n;
    }
}

// ---------- fallback VALU argmin (round-2 proven path) ----------
__global__ __launch_bounds__(256, 2)
void k_argmin_valu(const float* __restrict__ x, const float* __restrict__ w,
                   const float* __restrict__ wsq, const float* __restrict__ xsq,
                   int* __restrict__ idx, int* __restrict__ flags, int* __restrict__ flag_count) {
    __shared__ float xs[64 * 257];
    __shared__ float sd1[4][64];
    __shared__ float sd2[4][64];
    __shared__ int   si1[4][64];

    const int t = threadIdx.x;
    const int p = t & 63;
    const int q = t >> 6;
    const long n0 = (long)blockIdx.x * 64;
    const int b = (int)(n0 >> 12);
    const int hw0 = (int)(n0 & 4095);
    const float* xb = x + (long)b * DIM * HW + hw0;

    for (int i = 0; i < 64; ++i) {
        int c = q * 64 + i;
        xs[p * 257 + c] = xb[(long)c * HW + p];
    }
    __syncthreads();

    const float* xrow = xs + p * 257;
    const float s1 = xsq[n0 + p];
    float d1 = INFINITY, d2 = INFINITY;
    int i1 = 0;
    const int kbase = q * 256;
    const float* wq = w + (long)kbase * DIM;
    const float* wsq_q = wsq + kbase;

    for (int kc = 0; kc < 256; kc += 8) {
        float acc[8] = {0.f, 0.f, 0.f, 0.f, 0.f, 0.f, 0.f, 0.f};
        const float* w0 = wq + (long)kc * DIM;
#pragma unroll 2
        for (int d = 0; d < DIM; d += 4) {
            float x0 = xrow[d + 0];
            float x1 = xrow[d + 1];
            float x2 = xrow[d + 2];
            float x3 = xrow[d + 3];
#pragma unroll
            for (int j = 0; j < 8; ++j) {
                const float4 wv = *reinterpret_cast<const float4*>(w0 + j * DIM + d);
                acc[j] = __fmaf_rn(x0, wv.x, acc[j]);
                acc[j] = __fmaf_rn(x1, wv.y, acc[j]);
                acc[j] = __fmaf_rn(x2, wv.z, acc[j]);
                acc[j] = __fmaf_rn(x3, wv.w, acc[j]);
            }
        }
#pragma unroll
        for (int j = 0; j < 8; ++j) {
            float tk = __fadd_rn(s1, wsq_q[kc + j]);
            float dist = __fsub_rn(tk, __fmul_rn(2.0f, acc[j]));
            if (dist < d1) { d2 = d1; d1 = dist; i1 = kbase + kc + j; }
            else if (dist < d2) { d2 = dist; }
        }
    }

    sd1[q][p] = d1; sd2[q][p] = d2; si1[q][p] = i1;
    __syncthreads();
    if (q == 0) {
        float bd1 = sd1[0][p], bd2 = sd2[0][p];
        int bi = si1[0][p];
#pragma unroll
        for (int j = 1; j < 4; ++j) {
            float a1 = sd1[j][p], a2 = sd2[j][p];
            int ai = si1[j][p];
            if (a1 < bd1) { bd2 = fminf(bd1, a2); bd1 = a1; bi = ai; }
            else { bd2 = fminf(bd2, fminf(a1, a2)); }
        }
        const long n = n0 + p;
        idx[n] = bi;
        if (__fsub_rn(bd2, bd1) <= bd1 * 6.0e-7f) {
            int pos = atomicAdd(flag_count, 1);
            if (pos < MAX_FLAGS) flags[pos] = (int)n;
        }
    }
}

// ---------------------------------------------------------------------------
// exact-dot refine v3: BATCHED. One block = 8 flagged pixels x 1024 codes.
// 1024 threads, thread t = code t. x staged as f64 in LDS (broadcast reads);
// per d-step one coalesced wtr load feeds 8 independent f64 FMA chains ->
// w-stream amortized 8x, ILP 8. Same np-grid rounding; lexicographic
// (dist,index) wave-butterfly + cross-wave merge = first-index semantics.
// ---------------------------------------------------------------------------
__global__ __launch_bounds__(1024)
void k_refine(const float* __restrict__ x, const float* __restrict__ wtr,
              const float* __restrict__ wsq, const float* __restrict__ xsq,
              const int* __restrict__ flags, const int* __restrict__ flag_count,
              int* __restrict__ idx) {
    __shared__ double xsd[8][DIM];      // 16KB
    __shared__ int    np_s[8];
    __shared__ float  s1_s[8];
    __shared__ float  wd[16][8];
    __shared__ int    wi[16][8];

    int nf = *flag_count;
    if (nf > MAX_FLAGS) nf = MAX_FLAGS;
    const int t = threadIdx.x;
    const int lane = t & 63;
    const int wid = t >> 6;

    for (int base = blockIdx.x * 8; base < nf; base += gridDim.x * 8) {
        __syncthreads();   // protect LDS reuse across batches
        if (t < 8) {
            int fi = base + t;
            int n = flags[fi < nf ? fi : (nf - 1)];
            np_s[t] = n;
            s1_s[t] = xsq[n];
        }
        __syncthreads();
        // stage 8 x-vectors (2048 elements, 2 per thread) as f64
#pragma unroll
        for (int e = t; e < 2048; e += 1024) {
            int p = e >> 8, d = e & 255;
            int n = np_s[p];
            xsd[p][d] = (double)x[(long)(n >> 12) * (DIM * HW) + (long)d * HW + (n & 4095)];
        }
        __syncthreads();

        const float wq = wsq[t];
        double acc[8] = {0.0, 0.0, 0.0, 0.0, 0.0, 0.0, 0.0, 0.0};
#pragma unroll 4
        for (int d = 0; d < DIM; ++d) {
            double wk = (double)wtr[(long)d * NUM_K + t];
#pragma unroll
            for (int p = 0; p < 8; ++p) acc[p] = fma(wk, xsd[p][d], acc[p]);
        }

        float dkv[8];
        int   kiv[8];
#pragma unroll
        for (int p = 0; p < 8; ++p) {
            float dots = (float)acc[p];
            dkv[p] = __fsub_rn(__fadd_rn(s1_s[p], wq), __fmul_rn(2.0f, dots));
            kiv[p] = t;
        }
        // 64-lane butterfly, lexicographic (dist, index)
#pragma unroll
        for (int step = 1; step < 64; step <<= 1) {
#pragma unroll
            for (int p = 0; p < 8; ++p) {
                float od = __shfl_xor(dkv[p], step);
                int   oi = __shfl_xor(kiv[p], step);
                if (od < dkv[p] || (od == dkv[p] && oi < kiv[p])) { dkv[p] = od; kiv[p] = oi; }
            }
        }
        if (lane == 0) {
#pragma unroll
            for (int p = 0; p < 8; ++p) { wd[wid][p] = dkv[p]; wi[wid][p] = kiv[p]; }
        }
        __syncthreads();
        if (t < 8) {
            float bd = wd[0][t];
            int   bi = wi[0][t];
#pragma unroll
            for (int s = 1; s < 16; ++s) {
                float ad = wd[s][t];
                int   ai = wi[s][t];
                if (ad < bd || (ad == bd && ai < bi)) { bd = ad; bi = ai; }
            }
            if (base + t < nf) idx[np_s[t]] = bi;
        }
    }
}

// ---------- gather + straight-through + loss ----------
__global__ __launch_bounds__(256, 2)
void k_quant(const float* __restrict__ x, const float* __restrict__ w,
             const int* __restrict__ idx, float* __restrict__ qout,
             float* __restrict__ iout, float* __restrict__ loss) {
    __shared__ float wrow[64 * 257];
    __shared__ int lidx[64];
    __shared__ float part[4];
    const int t = threadIdx.x;
    const long n0 = (long)blockIdx.x * 64;
    const int b = (int)(n0 >> 12), hw0 = (int)(n0 & 4095);

    if (t < 64) lidx[t] = idx[n0 + t];
    __syncthreads();
    for (int i = 0; i < 64; ++i) {
        wrow[i * 257 + t] = w[(long)lidx[i] * DIM + t];
    }
    if (t < 64) iout[n0 + t] = (float)lidx[t];
    __syncthreads();

    const int p = t & 63, cg = t >> 6;
    const float* xb = x + (long)b * DIM * HW + hw0;
    float* qb = qout + (long)b * DIM * HW + hw0;
    float lsum = 0.f;
    for (int i = 0; i < 64; ++i) {
        int c = cg * 64 + i;
        float qv = wrow[p * 257 + c];
        long off = (long)c * HW + p;
        float xv = xb[off];
        float diff = __fsub_rn(qv, xv);
        qb[off] = __fadd_rn(xv, diff);
        lsum = __fmaf_rn(diff, diff, lsum);
    }
#pragma unroll
    for (int off = 32; off; off >>= 1) lsum += __shfl_down(lsum, off);
    if ((t & 63) == 0) part[t >> 6] = lsum;
    __syncthreads();
    if (t == 0) {
        float tot = (part[0] + part[1]) + (part[2] + part[3]);
        atomicAdd(loss, tot * (1.25f / 16777216.f));
    }
}

extern "C" void kernel_launch(void* const* d_in, const int* in_sizes, int n_in,
                              void* d_out, int out_size, void* d_ws, size_t ws_size,
                              hipStream_t stream) {
    const float* x = (const float*)d_in[0];
    const float* w = (const float*)d_in[1];

    float* qout = (float*)d_out;
    float* iout = qout + QELEMS;
    float* loss = iout + NPIX;

    char* wp = (char*)d_ws;
    int*   idx        = (int*)wp;                 wp += (size_t)NPIX * 4;        // 256KB
    float* wsq        = (float*)wp;               wp += (size_t)NUM_K * 4;       // 4KB
    float* xsq        = (float*)wp;               wp += (size_t)NPIX * 4;        // 256KB
    int*   flags      = (int*)wp;                 wp += (size_t)MAX_FLAGS * 4;   // 64KB
    int*   flag_count = (int*)wp;                 wp += 256;
    float* wtr        = (float*)wp;               wp += (size_t)NUM_K * DIM * 4; // 1MB
    short* whi        = (short*)wp;               wp += (size_t)NUM_K * DIM * 2; // 512KB
    float* pd1        = (float*)wp;               wp += (size_t)8 * NPIX * 4;    // 2MB
    float* pd2        = (float*)wp;               wp += (size_t)8 * NPIX * 4;    // 2MB
    int*   pi1        = (int*)wp;                 wp += (size_t)8 * NPIX * 4;    // 2MB
    size_t need = (size_t)(wp - (char*)d_ws);

    hipMemsetAsync(loss, 0, sizeof(float), stream);
    hipMemsetAsync(flag_count, 0, sizeof(int), stream);

    k_wsq<<<4, 256, 0, stream>>>(w, wsq);
    k_xsq<<<NPIX / 256, 256, 0, stream>>>(x, xsq);
    k_wtrans<<<DIM, 1024, 0, stream>>>(w, wtr);

    if (ws_size >= need) {
        k_wfrag<<<128, 256, 0, stream>>>(w, whi);
        k_argmin_mfma<<<2048, 256, 0, stream>>>(x, whi, wsq, xsq, pd1, pd2, pi1);
        k_combine<<<NPIX / 256, 256, 0, stream>>>(pd1, pd2, pi1, idx, flags, flag_count);
    } else {
        k_argmin_valu<<<NPIX / 64, 256, 0, stream>>>(x, w, wsq, xsq, idx, flags, flag_count);
    }
    k_refine<<<512, 1024, 0, stream>>>(x, wtr, wsq, xsq, flags, flag_count, idx);
    k_quant<<<NPIX / 64, 256, 0, stream>>>(x, w, idx, qout, iout, loss);
}

// Round 9
// 236.978 us; speedup vs baseline: 3.3929x; 1.1358x over previous
//
#include <hip/hip_runtime.h>
#include <math.h>

#define NUM_K 1024
#define DIM 256
#define HW 4096          // 64*64
#define NPIX 65536       // 16*4096
#define QELEMS 16777216  // 16*256*4096
#define MAX_FLAGS 16384

typedef short bf16x8 __attribute__((ext_vector_type(8)));
typedef float f32x4 __attribute__((ext_vector_type(4)));

__device__ __forceinline__ unsigned short f32_to_bf16_rne(float f) {
    unsigned int u = __float_as_uint(f);
    unsigned int r = u + 0x7FFFu + ((u >> 16) & 1u);
    return (unsigned short)(r >> 16);
}
__device__ __forceinline__ float bf16_to_f32(unsigned short h) {
    return __uint_as_float(((unsigned int)h) << 16);
}

// merge two lex-sorted top-3 states (A in-place; B from other lane/slice).
// Entries ordered by (dist, index); 3rd entry tracks dist only.
__device__ __forceinline__ void merge3(float& a1d, int& a1i, float& a2d, int& a2i, float& a3d,
                                       float b1d, int b1i, float b2d, int b2i, float b3d) {
    bool bf = (b1d < a1d) || (b1d == a1d && b1i < a1i);
    float r1d = bf ? b1d : a1d; int r1i = bf ? b1i : a1i;
    float n2d = bf ? b2d : a2d; int n2i = bf ? b2i : a2i;   // same-side second
    float o1d = bf ? a1d : b1d; int o1i = bf ? a1i : b1i;   // other-side first
    bool k2 = (n2d < o1d) || (n2d == o1d && n2i < o1i);
    float r2d = k2 ? n2d : o1d; int r2i = k2 ? n2i : o1i;
    float sm3 = bf ? b3d : a3d;                              // same-side third
    float o2d = bf ? a2d : b2d;                              // other-side second
    float r3d = k2 ? fminf(sm3, o1d) : fminf(n2d, o2d);
    a1d = r1d; a1i = r1i; a2d = r2d; a2i = r2i; a3d = r3d;
}

// ---------------------------------------------------------------------------
// numpy-replicated f32 sum of squares over 256 elements (pairwise SIMD tree).
// (validated bit-exact vs harness numpy in rounds 2-8)
// ---------------------------------------------------------------------------
__device__ __forceinline__ float np_sumsq_256(const float* __restrict__ p, long stride) {
    float blk0 = 0.f, blk1 = 0.f;
#pragma unroll
    for (int h = 0; h < 2; ++h) {
        const float* base = p + (long)h * 128 * stride;
        float s[16];
#pragma unroll
        for (int L = 0; L < 16; ++L) {
            float a0 = base[(long)(L)       * stride]; a0 = __fmul_rn(a0, a0);
            float a1 = base[(long)(16 + L)  * stride]; a1 = __fmul_rn(a1, a1);
            float a2 = base[(long)(32 + L)  * stride]; a2 = __fmul_rn(a2, a2);
            float a3 = base[(long)(48 + L)  * stride]; a3 = __fmul_rn(a3, a3);
            float a4 = base[(long)(64 + L)  * stride]; a4 = __fmul_rn(a4, a4);
            float a5 = base[(long)(80 + L)  * stride]; a5 = __fmul_rn(a5, a5);
            float a6 = base[(long)(96 + L)  * stride]; a6 = __fmul_rn(a6, a6);
            float a7 = base[(long)(112 + L) * stride]; a7 = __fmul_rn(a7, a7);
            float t1 = __fadd_rn(a0, a1);
            float t2 = __fadd_rn(a2, a3);
            float t3 = __fadd_rn(a4, a5);
            float t4 = __fadd_rn(a6, a7);
            s[L] = __fadd_rn(__fadd_rn(t1, t2), __fadd_rn(t3, t4));
        }
        float c0 = __fadd_rn(s[0], s[8]);
        float c1 = __fadd_rn(s[1], s[9]);
        float c2 = __fadd_rn(s[2], s[10]);
        float c3 = __fadd_rn(s[3], s[11]);
        float c4 = __fadd_rn(s[4], s[12]);
        float c5 = __fadd_rn(s[5], s[13]);
        float c6 = __fadd_rn(s[6], s[14]);
        float c7 = __fadd_rn(s[7], s[15]);
        float d0 = __fadd_rn(c0, c4);
        float d1 = __fadd_rn(c1, c5);
        float d2 = __fadd_rn(c2, c6);
        float d3 = __fadd_rn(c3, c7);
        float e0 = __fadd_rn(d0, d2);
        float e1 = __fadd_rn(d1, d3);
        float r  = __fadd_rn(e0, e1);
        if (h == 0) blk0 = r; else blk1 = r;
    }
    return __fadd_rn(blk0, blk1);
}

__global__ __launch_bounds__(256) void k_wsq(const float* __restrict__ w, float* __restrict__ wsq) {
    int k = blockIdx.x * 256 + threadIdx.x;
    if (k < NUM_K) wsq[k] = np_sumsq_256(w + (long)k * DIM, 1);
}

__global__ __launch_bounds__(256) void k_xsq(const float* __restrict__ x, float* __restrict__ xsq) {
    int n = blockIdx.x * 256 + threadIdx.x;
    int b = n >> 12, hw = n & 4095;
    xsq[n] = np_sumsq_256(x + (long)b * DIM * HW + hw, HW);
}

// ---------- w transpose: wtr[d][k] = w[k][d] ----------
__global__ __launch_bounds__(1024)
void k_wtrans(const float* __restrict__ w, float* __restrict__ wtr) {
    int d = blockIdx.x;
    int k = threadIdx.x;
    wtr[(long)d * NUM_K + k] = w[(long)k * DIM + d];
}

// ---------- w -> frag-major bf16 (hi only) ----------
__global__ __launch_bounds__(256)
void k_wfrag(const float* __restrict__ w, short* __restrict__ whi) {
    int id = blockIdx.x * 256 + threadIdx.x;   // 32768 = 1024 codes * 32 chunks
    int code = id >> 5;
    int c = id & 31;
    const float* src = w + (long)code * DIM + c * 8;
    bf16x8 vh;
#pragma unroll
    for (int j = 0; j < 8; ++j) vh[j] = (short)f32_to_bf16_rne(src[j]);
    int fl = ((c & 3) << 4) | (code & 15);
    long addr = ((((long)(code >> 4) * 8 + (c >> 2)) * 64 + fl) * 8);
    *(bf16x8*)(whi + addr) = vh;
}

// ---------------------------------------------------------------------------
// MFMA argmin v8: round-7 main loop (64px x 512 codes, 4 waves, 2-product,
// depth-4 B ring) + TOP-3 tracking epilogue (d1,i1,d2,i2,d3) with lex merges,
// in-block cross-wave combine -> per-slice partials.
// ---------------------------------------------------------------------------
#define A_SLOT(ks,m,fl) ((((ks)*4+(m))*64+(fl))*8)

__global__ __launch_bounds__(256, 2)
void k_argmin_mfma(const float* __restrict__ x,
                   const short* __restrict__ whi,
                   const float* __restrict__ wsq, const float* __restrict__ xsq,
                   float* __restrict__ pd1, int* __restrict__ pi1,
                   float* __restrict__ pd2, int* __restrict__ pi2,
                   float* __restrict__ pd3) {
    __shared__ short ahi[8 * 4 * 64 * 8];   // 32KB
    __shared__ short alo[8 * 4 * 64 * 8];   // 32KB
    __shared__ float cd1[4][64], cd2[4][64], cd3[4][64];
    __shared__ int   ci1[4][64], ci2[4][64];

    const int t = threadIdx.x;
    const int lane = t & 63;
    const int q = t >> 6;
    const int tile = blockIdx.x >> 1;
    const int slice = blockIdx.x & 1;

    const int b = tile >> 6;
    const int hw0 = (tile & 63) * 64;
    const float* xb = x + (long)b * (DIM * HW) + hw0 + lane;

#pragma unroll
    for (int i = 0; i < 8; ++i) {
        int c = q * 8 + i;
        float v[8];
#pragma unroll
        for (int jj = 0; jj < 8; ++jj) v[jj] = xb[(long)(c * 8 + jj) * HW];
        bf16x8 vh, vl;
#pragma unroll
        for (int jj = 0; jj < 8; ++jj) {
            unsigned short hh = f32_to_bf16_rne(v[jj]);
            float r = __fsub_rn(v[jj], bf16_to_f32(hh));
            vh[jj] = (short)hh;
            vl[jj] = (short)f32_to_bf16_rne(r);
        }
        int slot = A_SLOT(c >> 2, lane >> 4, ((c & 3) << 4) | (lane & 15));
        *(bf16x8*)(ahi + slot) = vh;
        *(bf16x8*)(alo + slot) = vl;
    }
    __syncthreads();

    const int ct0 = slice * 32 + q * 8;
    f32x4 acc[4][8];
#pragma unroll
    for (int m = 0; m < 4; ++m)
#pragma unroll
        for (int n = 0; n < 8; ++n) acc[m][n] = (f32x4){0.f, 0.f, 0.f, 0.f};

#define BADDR(i) ((((long)(ct0 + ((i) & 7)) * 8 + ((i) >> 3)) * 64 + lane) * 8)
    bf16x8 bring[4];
#pragma unroll
    for (int i = 0; i < 4; ++i) bring[i] = *(const bf16x8*)(whi + BADDR(i));

    bf16x8 ah[4], al[4];
#pragma unroll
    for (int i = 0; i < 64; ++i) {
        const int ks = i >> 3;
        const int n = i & 7;
        if (n == 0) {
#pragma unroll
            for (int m = 0; m < 4; ++m) {
                ah[m] = *(const bf16x8*)(ahi + A_SLOT(ks, m, lane));
                al[m] = *(const bf16x8*)(alo + A_SLOT(ks, m, lane));
            }
        }
        bf16x8 bcur = bring[i & 3];
        if (i + 4 < 64) bring[i & 3] = *(const bf16x8*)(whi + BADDR(i + 4));
#pragma unroll
        for (int m = 0; m < 4; ++m) {
            acc[m][n] = __builtin_amdgcn_mfma_f32_16x16x32_bf16(ah[m], bcur, acc[m][n], 0, 0, 0);
            acc[m][n] = __builtin_amdgcn_mfma_f32_16x16x32_bf16(al[m], bcur, acc[m][n], 0, 0, 0);
        }
    }
#undef BADDR

    // ---- epilogue: np-grid dist + per-lane top-3 ----
    const long px0 = (long)tile * 64;
    const int rbase = (lane >> 4) * 4;
    float s1v[4][4];
#pragma unroll
    for (int m = 0; m < 4; ++m)
#pragma unroll
        for (int r = 0; r < 4; ++r) s1v[m][r] = xsq[px0 + 16 * m + rbase + r];

    float e1d[4][4], e2d[4][4], e3d[4][4];
    int   e1i[4][4], e2i[4][4];
#pragma unroll
    for (int m = 0; m < 4; ++m)
#pragma unroll
        for (int r = 0; r < 4; ++r) {
            e1d[m][r] = INFINITY; e2d[m][r] = INFINITY; e3d[m][r] = INFINITY;
            e1i[m][r] = 0; e2i[m][r] = 0;
        }

#pragma unroll
    for (int n = 0; n < 8; ++n) {
        int code = (ct0 + n) * 16 + (lane & 15);
        float wq = wsq[code];
#pragma unroll
        for (int m = 0; m < 4; ++m) {
#pragma unroll
            for (int r = 0; r < 4; ++r) {
                float tt = __fadd_rn(s1v[m][r], wq);
                float dist = __fmaf_rn(-2.0f, acc[m][n][r], tt);
                bool c1 = dist < e1d[m][r];
                bool c2 = dist < e2d[m][r];
                bool c3 = dist < e3d[m][r];
                float n3 = c2 ? e2d[m][r] : (c3 ? dist : e3d[m][r]);
                float n2 = c1 ? e1d[m][r] : (c2 ? dist : e2d[m][r]);
                int   j2 = c1 ? e1i[m][r] : (c2 ? code : e2i[m][r]);
                float n1 = c1 ? dist : e1d[m][r];
                int   j1 = c1 ? code : e1i[m][r];
                e3d[m][r] = n3; e2d[m][r] = n2; e2i[m][r] = j2;
                e1d[m][r] = n1; e1i[m][r] = j1;
            }
        }
    }

    // 16-lane butterfly with lex top-3 merge
#pragma unroll
    for (int step = 1; step < 16; step <<= 1) {
#pragma unroll
        for (int m = 0; m < 4; ++m) {
#pragma unroll
            for (int r = 0; r < 4; ++r) {
                float o1 = __shfl_xor(e1d[m][r], step);
                int   p1 = __shfl_xor(e1i[m][r], step);
                float o2 = __shfl_xor(e2d[m][r], step);
                int   p2 = __shfl_xor(e2i[m][r], step);
                float o3 = __shfl_xor(e3d[m][r], step);
                merge3(e1d[m][r], e1i[m][r], e2d[m][r], e2i[m][r], e3d[m][r],
                       o1, p1, o2, p2, o3);
            }
        }
    }

    // per-wave results -> LDS
    if ((lane & 15) == 0) {
#pragma unroll
        for (int m = 0; m < 4; ++m) {
#pragma unroll
            for (int r = 0; r < 4; ++r) {
                int px = 16 * m + rbase + r;
                cd1[q][px] = e1d[m][r]; ci1[q][px] = e1i[m][r];
                cd2[q][px] = e2d[m][r]; ci2[q][px] = e2i[m][r];
                cd3[q][px] = e3d[m][r];
            }
        }
    }
    __syncthreads();

    // cross-wave combine (ascending code order) -> per-slice partials
    if (t < 64) {
        float d1 = cd1[0][t], d2 = cd2[0][t], d3 = cd3[0][t];
        int   i1 = ci1[0][t], i2 = ci2[0][t];
#pragma unroll
        for (int s = 1; s < 4; ++s) {
            merge3(d1, i1, d2, i2, d3, cd1[s][t], ci1[s][t], cd2[s][t], ci2[s][t], cd3[s][t]);
        }
        long n = (long)slice * NPIX + px0 + t;
        pd1[n] = d1; pi1[n] = i1; pd2[n] = d2; pi2[n] = i2; pd3[n] = d3;
    }
}

// ---------- combine 2 code-slice partials, classify: done / pair / full ----------
__global__ __launch_bounds__(256)
void k_combine(const float* __restrict__ pd1, const int* __restrict__ pi1,
               const float* __restrict__ pd2, const int* __restrict__ pi2,
               const float* __restrict__ pd3, int* __restrict__ idx,
               int4* __restrict__ pairf, int* __restrict__ paircnt,
               int* __restrict__ fullf, int* __restrict__ fullcnt) {
    int n = blockIdx.x * 256 + threadIdx.x;
    float d1 = pd1[n], d2 = pd2[n], d3 = pd3[n];
    int   i1 = pi1[n], i2 = pi2[n];
    long n1 = (long)NPIX + n;
    merge3(d1, i1, d2, i2, d3, pd1[n1], pi1[n1], pd2[n1], pi2[n1], pd3[n1]);
    idx[n] = i1;
    float m = d1 * 1.0e-6f;
    if (__fsub_rn(d3, d1) <= m) {
        int pos = atomicAdd(fullcnt, 1);
        if (pos < MAX_FLAGS) fullf[pos] = n;
    } else if (__fsub_rn(d2, d1) <= m) {
        int pos = atomicAdd(paircnt, 1);
        if (pos < MAX_FLAGS) pairf[pos] = (int4){n, i1, i2, 0};
    }
}

// ---------- fallback VALU argmin (round-2 proven; emits full-flags only) ----------
__global__ __launch_bounds__(256, 2)
void k_argmin_valu(const float* __restrict__ x, const float* __restrict__ w,
                   const float* __restrict__ wsq, const float* __restrict__ xsq,
                   int* __restrict__ idx, int* __restrict__ fullf, int* __restrict__ fullcnt) {
    __shared__ float xs[64 * 257];
    __shared__ float sd1[4][64];
    __shared__ float sd2[4][64];
    __shared__ int   si1[4][64];

    const int t = threadIdx.x;
    const int p = t & 63;
    const int q = t >> 6;
    const long n0 = (long)blockIdx.x * 64;
    const int b = (int)(n0 >> 12);
    const int hw0 = (int)(n0 & 4095);
    const float* xb = x + (long)b * DIM * HW + hw0;

    for (int i = 0; i < 64; ++i) {
        int c = q * 64 + i;
        xs[p * 257 + c] = xb[(long)c * HW + p];
    }
    __syncthreads();

    const float* xrow = xs + p * 257;
    const float s1 = xsq[n0 + p];
    float d1 = INFINITY, d2 = INFINITY;
    int i1 = 0;
    const int kbase = q * 256;
    const float* wq = w + (long)kbase * DIM;
    const float* wsq_q = wsq + kbase;

    for (int kc = 0; kc < 256; kc += 8) {
        float acc[8] = {0.f, 0.f, 0.f, 0.f, 0.f, 0.f, 0.f, 0.f};
        const float* w0 = wq + (long)kc * DIM;
#pragma unroll 2
        for (int d = 0; d < DIM; d += 4) {
            float x0 = xrow[d + 0];
            float x1 = xrow[d + 1];
            float x2 = xrow[d + 2];
            float x3 = xrow[d + 3];
#pragma unroll
            for (int j = 0; j < 8; ++j) {
                const float4 wv = *reinterpret_cast<const float4*>(w0 + j * DIM + d);
                acc[j] = __fmaf_rn(x0, wv.x, acc[j]);
                acc[j] = __fmaf_rn(x1, wv.y, acc[j]);
                acc[j] = __fmaf_rn(x2, wv.z, acc[j]);
                acc[j] = __fmaf_rn(x3, wv.w, acc[j]);
            }
        }
#pragma unroll
        for (int j = 0; j < 8; ++j) {
            float tk = __fadd_rn(s1, wsq_q[kc + j]);
            float dist = __fsub_rn(tk, __fmul_rn(2.0f, acc[j]));
            if (dist < d1) { d2 = d1; d1 = dist; i1 = kbase + kc + j; }
            else if (dist < d2) { d2 = dist; }
        }
    }

    sd1[q][p] = d1; sd2[q][p] = d2; si1[q][p] = i1;
    __syncthreads();
    if (q == 0) {
        float bd1 = sd1[0][p], bd2 = sd2[0][p];
        int bi = si1[0][p];
#pragma unroll
        for (int j = 1; j < 4; ++j) {
            float a1 = sd1[j][p], a2 = sd2[j][p];
            int ai = si1[j][p];
            if (a1 < bd1) { bd2 = fminf(bd1, a2); bd1 = a1; bi = ai; }
            else { bd2 = fminf(bd2, fminf(a1, a2)); }
        }
        const long n = n0 + p;
        idx[n] = bi;
        if (__fsub_rn(bd2, bd1) <= bd1 * 6.0e-7f) {
            int pos = atomicAdd(fullcnt, 1);
            if (pos < MAX_FLAGS) fullf[pos] = (int)n;
        }
    }
}

// ---------------------------------------------------------------------------
// pair refine: one WAVE per flagged pixel; exact f64 dots for the 2 candidate
// codes only; butterfly f64 sum; np-grid dist; lex (dist,index) winner.
// ---------------------------------------------------------------------------
__global__ __launch_bounds__(256)
void k_refine_pair(const float* __restrict__ x, const float* __restrict__ w,
                   const float* __restrict__ wsq, const float* __restrict__ xsq,
                   const int4* __restrict__ pairf, const int* __restrict__ paircnt,
                   int* __restrict__ idx) {
    int np = *paircnt;
    if (np > MAX_FLAGS) np = MAX_FLAGS;
    const int lane = threadIdx.x & 63;
    const int wv = threadIdx.x >> 6;
    for (int fi = blockIdx.x * 4 + wv; fi < np; fi += gridDim.x * 4) {
        int4 f = pairf[fi];
        int n = f.x, c1 = f.y, c2 = f.z;
        int b = n >> 12, hw = n & 4095;
        const float* xp = x + (long)b * (DIM * HW) + hw;
        double xd0 = (double)xp[(long)(lane * 4 + 0) * HW];
        double xd1 = (double)xp[(long)(lane * 4 + 1) * HW];
        double xd2 = (double)xp[(long)(lane * 4 + 2) * HW];
        double xd3 = (double)xp[(long)(lane * 4 + 3) * HW];
        const float4 w1 = *reinterpret_cast<const float4*>(w + (long)c1 * DIM + lane * 4);
        const float4 w2 = *reinterpret_cast<const float4*>(w + (long)c2 * DIM + lane * 4);
        double s1 = fma((double)w1.x, xd0, fma((double)w1.y, xd1,
                    fma((double)w1.z, xd2, (double)w1.w * xd3)));
        double s2 = fma((double)w2.x, xd0, fma((double)w2.y, xd1,
                    fma((double)w2.z, xd2, (double)w2.w * xd3)));
#pragma unroll
        for (int st = 1; st < 64; st <<= 1) {
            s1 += __shfl_xor(s1, st);
            s2 += __shfl_xor(s2, st);
        }
        if (lane == 0) {
            float xq = xsq[n];
            float dk1 = __fsub_rn(__fadd_rn(xq, wsq[c1]), __fmul_rn(2.0f, (float)s1));
            float dk2 = __fsub_rn(__fadd_rn(xq, wsq[c2]), __fmul_rn(2.0f, (float)s2));
            bool take2 = (dk2 < dk1) || (dk2 == dk1 && c2 < c1);
            idx[n] = take2 ? c2 : c1;
        }
    }
}

// ---------------------------------------------------------------------------
// full refine: 4 pixels x 1024 codes per block; x staged f32 [d][4] in LDS
// (1 ds_read_b128 per d-step); 4 f64 chains; butterfly + cross-wave lex merge.
// ---------------------------------------------------------------------------
__global__ __launch_bounds__(1024)
void k_refine_full(const float* __restrict__ x, const float* __restrict__ wtr,
                   const float* __restrict__ wsq, const float* __restrict__ xsq,
                   const int* __restrict__ fullf, const int* __restrict__ fullcnt,
                   int* __restrict__ idx) {
    __shared__ float xsf[DIM][4];       // 4KB
    __shared__ int   np_s[4];
    __shared__ float s1_s[4];
    __shared__ float wd[16][4];
    __shared__ int   wi[16][4];

    int nf = *fullcnt;
    if (nf > MAX_FLAGS) nf = MAX_FLAGS;
    const int t = threadIdx.x;
    const int lane = t & 63;
    const int wid = t >> 6;

    for (int base = blockIdx.x * 4; base < nf; base += gridDim.x * 4) {
        __syncthreads();
        if (t < 4) {
            int fi = base + t;
            int n = fullf[fi < nf ? fi : (nf - 1)];
            np_s[t] = n;
            s1_s[t] = xsq[n];
        }
        __syncthreads();
        {
            int p = t & 3, d = t >> 2;
            int n = np_s[p];
            xsf[d][p] = x[(long)(n >> 12) * (DIM * HW) + (long)d * HW + (n & 4095)];
        }
        __syncthreads();

        const float wq = wsq[t];
        double a0 = 0.0, a1 = 0.0, a2 = 0.0, a3 = 0.0;
#pragma unroll 4
        for (int d = 0; d < DIM; ++d) {
            double wk = (double)wtr[(long)d * NUM_K + t];
            float4 xv = *reinterpret_cast<const float4*>(&xsf[d][0]);
            a0 = fma(wk, (double)xv.x, a0);
            a1 = fma(wk, (double)xv.y, a1);
            a2 = fma(wk, (double)xv.z, a2);
            a3 = fma(wk, (double)xv.w, a3);
        }
        float dkv[4];
        int   kiv[4];
        dkv[0] = __fsub_rn(__fadd_rn(s1_s[0], wq), __fmul_rn(2.0f, (float)a0));
        dkv[1] = __fsub_rn(__fadd_rn(s1_s[1], wq), __fmul_rn(2.0f, (float)a1));
        dkv[2] = __fsub_rn(__fadd_rn(s1_s[2], wq), __fmul_rn(2.0f, (float)a2));
        dkv[3] = __fsub_rn(__fadd_rn(s1_s[3], wq), __fmul_rn(2.0f, (float)a3));
#pragma unroll
        for (int p = 0; p < 4; ++p) kiv[p] = t;

#pragma unroll
        for (int step = 1; step < 64; step <<= 1) {
#pragma unroll
            for (int p = 0; p < 4; ++p) {
                float od = __shfl_xor(dkv[p], step);
                int   oi = __shfl_xor(kiv[p], step);
                if (od < dkv[p] || (od == dkv[p] && oi < kiv[p])) { dkv[p] = od; kiv[p] = oi; }
            }
        }
        if (lane == 0) {
#pragma unroll
            for (int p = 0; p < 4; ++p) { wd[wid][p] = dkv[p]; wi[wid][p] = kiv[p]; }
        }
        __syncthreads();
        if (t < 4) {
            float bd = wd[0][t];
            int   bi = wi[0][t];
#pragma unroll
            for (int s = 1; s < 16; ++s) {
                float ad = wd[s][t];
                int   ai = wi[s][t];
                if (ad < bd || (ad == bd && ai < bi)) { bd = ad; bi = ai; }
            }
            if (base + t < nf) idx[np_s[t]] = bi;
        }
    }
}

// ---------- gather + straight-through + loss ----------
__global__ __launch_bounds__(256, 2)
void k_quant(const float* __restrict__ x, const float* __restrict__ w,
             const int* __restrict__ idx, float* __restrict__ qout,
             float* __restrict__ iout, float* __restrict__ loss) {
    __shared__ float wrow[64 * 257];
    __shared__ int lidx[64];
    __shared__ float part[4];
    const int t = threadIdx.x;
    const long n0 = (long)blockIdx.x * 64;
    const int b = (int)(n0 >> 12), hw0 = (int)(n0 & 4095);

    if (t < 64) lidx[t] = idx[n0 + t];
    __syncthreads();
    for (int i = 0; i < 64; ++i) {
        wrow[i * 257 + t] = w[(long)lidx[i] * DIM + t];
    }
    if (t < 64) iout[n0 + t] = (float)lidx[t];
    __syncthreads();

    const int p = t & 63, cg = t >> 6;
    const float* xb = x + (long)b * DIM * HW + hw0;
    float* qb = qout + (long)b * DIM * HW + hw0;
    float lsum = 0.f;
    for (int i = 0; i < 64; ++i) {
        int c = cg * 64 + i;
        float qv = wrow[p * 257 + c];
        long off = (long)c * HW + p;
        float xv = xb[off];
        float diff = __fsub_rn(qv, xv);
        qb[off] = __fadd_rn(xv, diff);
        lsum = __fmaf_rn(diff, diff, lsum);
    }
#pragma unroll
    for (int off = 32; off; off >>= 1) lsum += __shfl_down(lsum, off);
    if ((t & 63) == 0) part[t >> 6] = lsum;
    __syncthreads();
    if (t == 0) {
        float tot = (part[0] + part[1]) + (part[2] + part[3]);
        atomicAdd(loss, tot * (1.25f / 16777216.f));
    }
}

extern "C" void kernel_launch(void* const* d_in, const int* in_sizes, int n_in,
                              void* d_out, int out_size, void* d_ws, size_t ws_size,
                              hipStream_t stream) {
    const float* x = (const float*)d_in[0];
    const float* w = (const float*)d_in[1];

    float* qout = (float*)d_out;
    float* iout = qout + QELEMS;
    float* loss = iout + NPIX;

    char* wp = (char*)d_ws;
    int*   idx     = (int*)wp;      wp += (size_t)NPIX * 4;           // 256KB
    float* wsq     = (float*)wp;    wp += (size_t)NUM_K * 4;          // 4KB
    float* xsq     = (float*)wp;    wp += (size_t)NPIX * 4;           // 256KB
    int4*  pairf   = (int4*)wp;     wp += (size_t)MAX_FLAGS * 16;     // 256KB
    int*   paircnt = (int*)wp;      wp += 256;
    int*   fullf   = (int*)wp;      wp += (size_t)MAX_FLAGS * 4;      // 64KB
    int*   fullcnt = (int*)wp;      wp += 256;
    float* wtr     = (float*)wp;    wp += (size_t)NUM_K * DIM * 4;    // 1MB
    short* whi     = (short*)wp;    wp += (size_t)NUM_K * DIM * 2;    // 512KB
    float* pd1     = (float*)wp;    wp += (size_t)2 * NPIX * 4;       // 512KB
    int*   pi1     = (int*)wp;      wp += (size_t)2 * NPIX * 4;
    float* pd2     = (float*)wp;    wp += (size_t)2 * NPIX * 4;
    int*   pi2     = (int*)wp;      wp += (size_t)2 * NPIX * 4;
    float* pd3     = (float*)wp;    wp += (size_t)2 * NPIX * 4;
    size_t need = (size_t)(wp - (char*)d_ws);

    hipMemsetAsync(loss, 0, sizeof(float), stream);
    hipMemsetAsync(paircnt, 0, sizeof(int), stream);
    hipMemsetAsync(fullcnt, 0, sizeof(int), stream);

    k_wsq<<<4, 256, 0, stream>>>(w, wsq);
    k_xsq<<<NPIX / 256, 256, 0, stream>>>(x, xsq);
    k_wtrans<<<DIM, 1024, 0, stream>>>(w, wtr);

    if (ws_size >= need) {
        k_wfrag<<<128, 256, 0, stream>>>(w, whi);
        k_argmin_mfma<<<2048, 256, 0, stream>>>(x, whi, wsq, xsq, pd1, pi1, pd2, pi2, pd3);
        k_combine<<<NPIX / 256, 256, 0, stream>>>(pd1, pi1, pd2, pi2, pd3, idx,
                                                  pairf, paircnt, fullf, fullcnt);
        k_refine_pair<<<2048, 256, 0, stream>>>(x, w, wsq, xsq, pairf, paircnt, idx);
    } else {
        k_argmin_valu<<<NPIX / 64, 256, 0, stream>>>(x, w, wsq, xsq, idx, fullf, fullcnt);
    }
    k_refine_full<<<1024, 1024, 0, stream>>>(x, wtr, wsq, xsq, fullf, fullcnt, idx);
    k_quant<<<NPIX / 64, 256, 0, stream>>>(x, w, idx, qout, iout, loss);
}